// Round 10
// baseline (382.920 us; speedup 1.0000x reference)
//
#include <hip/hip_runtime.h>
#include <math.h>

#define Nn 4096
#define Ee 32768
#define Bb 64
#define FINc 128
#define Dd 64
#define SIGf 0.15f
#define LAMf 0.01f
#define EPSf 1e-5f

typedef __attribute__((ext_vector_type(8))) short bf16x8;
typedef __attribute__((ext_vector_type(4))) float f32x4;

__device__ inline short f2bf(float f) {
  union { float f; unsigned u; } v; v.f = f;
  unsigned r = v.u + 0x7fffu + ((v.u >> 16) & 1u);
  return (short)(r >> 16);
}
__device__ inline float bf2f(unsigned short s) {
  union { unsigned u; float f; } v; v.u = ((unsigned)s) << 16; return v.f;
}
__device__ inline bf16x8 pack8v(f32x4 a, f32x4 b) {
  bf16x8 r;
  r[0]=f2bf(a.x); r[1]=f2bf(a.y); r[2]=f2bf(a.z); r[3]=f2bf(a.w);
  r[4]=f2bf(b.x); r[5]=f2bf(b.y); r[6]=f2bf(b.z); r[7]=f2bf(b.w);
  return r;
}
__device__ inline float sigm(float x) { return 1.f / (1.f + expf(-x)); }

// ---------------- prep: w2 LDS-tiled transpose + small packs + in-degree + tkl ----------------
__global__ __launch_bounds__(256) void k_prep(
    const float* __restrict__ w1, const float* __restrict__ w2,
    const float* __restrict__ b2, const float* __restrict__ rootw,
    const float* __restrict__ gwih, const float* __restrict__ gwhh,
    const float* __restrict__ preW, const float* __restrict__ preb,
    const float* __restrict__ postW, const float* __restrict__ postb,
    const float* __restrict__ outW, const float* __restrict__ outb,
    const int* __restrict__ dstIdx,
    short* __restrict__ w1T, short* __restrict__ b2T,
    short* __restrict__ w2T, short* __restrict__ rootwT,
    short* __restrict__ gwihB, short* __restrict__ gwhhB,
    short* __restrict__ preWT, float* __restrict__ cnt,
    float* __restrict__ y) {
  const int tid = threadIdx.x;
  const int bid = blockIdx.x;
  __shared__ float tile[64][65];
  __shared__ float red[256];

  if (bid < 192) {
    // transpose one 64x64 page: w2T[l][h][o][f] = w2[l][h][f][o]
    const float* srcp = w2 + (size_t)bid*4096;
    #pragma unroll
    for (int r = 0; r < 16; ++r) {
      int i2 = r*256 + tid;
      tile[i2 >> 6][i2 & 63] = srcp[i2];
    }
    __syncthreads();
    short* dstp = w2T + (size_t)bid*4096;
    #pragma unroll
    for (int r = 0; r < 16; ++r) {
      int i2 = r*256 + tid;
      dstp[i2] = f2bf(tile[i2 & 63][i2 >> 6]);
    }
  } else if (bid < 336) {
    int idx = (bid - 192)*256 + tid;
    if (idx < 3*64*64) {
      int f = idx & 63, h = (idx >> 6) & 63, l = idx >> 12;
      w1T[idx] = f2bf(w1[l*4096 + f*64 + h]);          // w1T[l][h][f]
      b2T[idx] = f2bf(b2[l*4096 + f*64 + h]);          // b2T[l][o][f]
      rootwT[idx] = f2bf(rootw[l*4096 + f*64 + h]);    // rootwT[l][d][k]
    }
    if (idx < 3*192*64) {
      gwihB[idx] = f2bf(gwih[idx]);
      gwhhB[idx] = f2bf(gwhh[idx]);
    }
    if (idx < 64*128) {
      int k = idx & 127, d = idx >> 7;
      preWT[idx] = f2bf(preW[k*64 + d]);               // preWT[d][k]
    }
    if (idx < Ee) atomicAdd(&cnt[dstIdx[idx]], 1.0f);
  } else {
    const float logc = logf(SIGf * sqrtf(6.28318530717958647692f));
    const float c2 = 0.5f / (SIGf * SIGf);
    float acc = 0.f;
    for (int i = tid; i < FINc*Dd; i += 256) { float w = preW[i];  acc += c2*w*w + logc; }
    for (int i = tid; i < Dd; i += 256)      { float w = preb[i];  acc += c2*w*w + logc; }
    for (int i = tid; i < Dd*Dd; i += 256)   { float w = postW[i]; acc += c2*w*w + logc; }
    for (int i = tid; i < Dd; i += 256)      { float w = postb[i]; acc += c2*w*w + logc; }
    for (int i = tid; i < Dd; i += 256)      { float w = outW[i];  acc += c2*w*w + logc; }
    if (tid == 0)                            { float w = outb[0];  acc += c2*w*w + logc; }
    red[tid] = acc; __syncthreads();
    for (int s = 128; s > 0; s >>= 1) { if (tid < s) red[tid] += red[tid+s]; __syncthreads(); }
    if (tid == 0) y[Bb] = red[0];
  }
}

// ---------------- pre FC + relu via MFMA (round-8 16-node version) ----------------
__global__ __launch_bounds__(256) void k_pre(const float* __restrict__ x,
                                             const short* __restrict__ preWT,
                                             const float* __restrict__ preb,
                                             float* __restrict__ out, float* __restrict__ h) {
  const int tid = threadIdx.x, lane = tid & 63, wave = tid >> 6;
  const int m15 = lane & 15, kq = lane >> 4;
  const int nb = blockIdx.x * 16;
  const f32x4 zero4 = {0.f,0.f,0.f,0.f};
  const int d = wave*16 + m15;
  bf16x8 bfr[4];
  #pragma unroll
  for (int c = 0; c < 4; ++c)
    bfr[c] = *(const bf16x8*)(preWT + d*128 + c*32 + kq*8);
  const float* xp = x + (size_t)(nb + m15)*128 + kq*8;
  f32x4 p = zero4;
  #pragma unroll
  for (int c = 0; c < 4; ++c) {
    bf16x8 a = pack8v(*(const f32x4*)(xp + c*32), *(const f32x4*)(xp + c*32 + 4));
    p = __builtin_amdgcn_mfma_f32_16x16x32_bf16(a, bfr[c], p, 0, 0, 0);
  }
  float bv = preb[d];
  #pragma unroll
  for (int r = 0; r < 4; ++r) {
    int node = nb + kq*4 + r;
    float v = fmaxf(p[r] + bv, 0.f);
    out[node*64 + d] = v;
    h[node*64 + d] = v;
  }
}

// ---------------- fused edge-MLP + bilinear message GEMM (MFMA) + scatter ----------------
// (byte-identical structure to round 8: 128 edges x 16 o per block, 2 waves,
// 4 blocks/CU, LDS-staged w2 with XOR swizzle, clean 64B atomic segments)
__global__ __launch_bounds__(128) void k_msg(
    const float* __restrict__ out, const float* __restrict__ edge_attr,
    const short* __restrict__ w1T, const float* __restrict__ b1,
    const short* __restrict__ w2T, const short* __restrict__ b2T,
    const int* __restrict__ src, const int* __restrict__ dst,
    float* __restrict__ agg, float* __restrict__ stats) {
  __shared__ short hidT[64*136];
  __shared__ __align__(16) short wstage[8192];
  __shared__ int srcv[128];
  __shared__ int dstv[128];

  const int tid  = threadIdx.x;
  const int lane = tid & 63;
  const int w    = tid >> 6;
  const int m15  = lane & 15;
  const int kq   = lane >> 4;
  const int ebi  = blockIdx.x & 255;
  const int os   = blockIdx.x >> 8;
  const int ebase = ebi * 128;
  const int we   = w*64;

  srcv[tid] = src[ebase + tid];
  dstv[tid] = dst[ebase + tid];
  if (blockIdx.x == 0) {
    for (int i = tid; i < 1280; i += 128) stats[i] = 0.f;   // [0,1280) only: ctrs live above
  }
  __syncthreads();

  const f32x4 zero4 = {0.f, 0.f, 0.f, 0.f};

  f32x4 s0, s1, s2, s3, s4, s5, s6, s7;
  {
    const short* pg = w2T + (size_t)(w*4)*4096 + os*1024 + lane*16;
    s0 = *(const f32x4*)(pg);          s1 = *(const f32x4*)(pg + 8);
    s2 = *(const f32x4*)(pg + 4096);   s3 = *(const f32x4*)(pg + 4104);
    s4 = *(const f32x4*)(pg + 8192);   s5 = *(const f32x4*)(pg + 8200);
    s6 = *(const f32x4*)(pg + 12288);  s7 = *(const f32x4*)(pg + 12296);
  }
  const int wb0 = (lane*32) ^ ((((lane*32) >> 7) & 7) << 4);
  const int wb1 = (lane*32 + 16) ^ ((((lane*32) >> 7) & 7) << 4);

  bf16x8 sfrag[4][2];
  #pragma unroll
  for (int t = 0; t < 4; ++t) {
    int node = srcv[we + t*16 + m15];
    const float* sp = out + node*64 + kq*8;
    #pragma unroll
    for (int ks = 0; ks < 2; ++ks)
      sfrag[t][ks] = pack8v(*(const f32x4*)(sp + ks*32), *(const f32x4*)(sp + ks*32 + 4));
  }

  {
    bf16x8 ea[4][2];
    #pragma unroll
    for (int t = 0; t < 4; ++t) {
      const float* ep = edge_attr + (size_t)(ebase + we + t*16 + m15)*64 + kq*8;
      ea[t][0] = pack8v(*(const f32x4*)(ep),      *(const f32x4*)(ep + 4));
      ea[t][1] = pack8v(*(const f32x4*)(ep + 32), *(const f32x4*)(ep + 36));
    }
    #pragma unroll
    for (int hg = 0; hg < 4; ++hg) {
      const short* wp = w1T + (hg*16 + m15)*64 + kq*8;
      bf16x8 bw0 = *(const bf16x8*)(wp);
      bf16x8 bw1 = *(const bf16x8*)(wp + 32);
      float b1v = b1[hg*16 + m15];
      #pragma unroll
      for (int t = 0; t < 4; ++t) {
        f32x4 p = __builtin_amdgcn_mfma_f32_16x16x32_bf16(ea[t][0], bw0, zero4, 0, 0, 0);
        p = __builtin_amdgcn_mfma_f32_16x16x32_bf16(ea[t][1], bw1, p, 0, 0, 0);
        ushort4 hp4;
        hp4.x = (unsigned short)f2bf(fmaxf(p.x + b1v, 0.f));
        hp4.y = (unsigned short)f2bf(fmaxf(p.y + b1v, 0.f));
        hp4.z = (unsigned short)f2bf(fmaxf(p.z + b1v, 0.f));
        hp4.w = (unsigned short)f2bf(fmaxf(p.w + b1v, 0.f));
        *(ushort4*)(hidT + (hg*16 + m15)*136 + we + t*16 + kq*4) = hp4;
      }
    }
  }

  f32x4 acc[4] = {zero4, zero4, zero4, zero4};
  const int ro0 = (m15*128 + kq*16) ^ ((m15 & 7) << 4);
  const int ro1 = (m15*128 + 64 + kq*16) ^ ((m15 & 7) << 4);

  for (int c = 0; c < 8; ++c) {
    __syncthreads();
    {
      char* wd = (char*)wstage + (w*4)*2048;
      *(f32x4*)(wd + wb0) = s0;          *(f32x4*)(wd + wb1) = s1;
      *(f32x4*)(wd + 2048 + wb0) = s2;   *(f32x4*)(wd + 2048 + wb1) = s3;
      *(f32x4*)(wd + 4096 + wb0) = s4;   *(f32x4*)(wd + 4096 + wb1) = s5;
      *(f32x4*)(wd + 6144 + wb0) = s6;   *(f32x4*)(wd + 6144 + wb1) = s7;
    }
    __syncthreads();
    if (c < 7) {
      const short* pg = w2T + (size_t)((c + 1)*8 + w*4)*4096 + os*1024 + lane*16;
      s0 = *(const f32x4*)(pg);          s1 = *(const f32x4*)(pg + 8);
      s2 = *(const f32x4*)(pg + 4096);   s3 = *(const f32x4*)(pg + 4104);
      s4 = *(const f32x4*)(pg + 8192);   s5 = *(const f32x4*)(pg + 8200);
      s6 = *(const f32x4*)(pg + 12288);  s7 = *(const f32x4*)(pg + 12296);
    }
    #pragma unroll 2
    for (int j = 0; j < 8; ++j) {
      const char* wbp = (const char*)wstage + j*2048;
      bf16x8 W0 = *(const bf16x8*)(wbp + ro0);
      bf16x8 W1 = *(const bf16x8*)(wbp + ro1);
      const unsigned short* hrow =
          (const unsigned short*)hidT + (c*8 + j)*136 + we + kq*4;
      #pragma unroll
      for (int t = 0; t < 4; ++t) {
        f32x4 p = __builtin_amdgcn_mfma_f32_16x16x32_bf16(sfrag[t][0], W0, zero4, 0, 0, 0);
        p = __builtin_amdgcn_mfma_f32_16x16x32_bf16(sfrag[t][1], W1, p, 0, 0, 0);
        ushort4 hu = *(const ushort4*)(hrow + t*16);
        acc[t].x += bf2f(hu.x) * p.x;
        acc[t].y += bf2f(hu.y) * p.y;
        acc[t].z += bf2f(hu.z) * p.z;
        acc[t].w += bf2f(hu.w) * p.w;
      }
    }
  }

  {
    const short* Bp = b2T + (os*16 + m15)*64 + kq*8;
    bf16x8 W0 = *(const bf16x8*)(Bp);
    bf16x8 W1 = *(const bf16x8*)(Bp + 32);
    #pragma unroll
    for (int t = 0; t < 4; ++t) {
      f32x4 p = __builtin_amdgcn_mfma_f32_16x16x32_bf16(sfrag[t][0], W0, zero4, 0, 0, 0);
      p = __builtin_amdgcn_mfma_f32_16x16x32_bf16(sfrag[t][1], W1, p, 0, 0, 0);
      acc[t] += p;
    }
  }

  #pragma unroll
  for (int t = 0; t < 4; ++t) {
    #pragma unroll
    for (int r = 0; r < 4; ++r) {
      int e = we + t*16 + kq*4 + r;
      atomicAdd(&agg[((size_t)os*Nn + dstv[e])*16 + m15], acc[t][r]);
    }
  }
}

// ---------------- fused m/softmax/BN-stats + grid-sync + DGN/GRU/residual/pool ----------------
// Replaces k_m_fused + k_gru. 16 nodes/block, grid 256 (all blocks co-resident:
// 256 blocks x 256 thr x ~26KB LDS on 256 CUs). After the BN-stats atomics, a
// device-scope counter sync (stats[1280+layer], zeroed by host memset) gates
// the DGN phase that needs all-node stats. m and s stay in LDS across the sync
// (no m/sbuf global round-trip). Post-sync stats reads use device-scope atomic
// loads (G12/G16: per-XCD L2 not coherent for plain loads).
__global__ __launch_bounds__(256) void k_mgru(
    float* __restrict__ agg, const float* __restrict__ cnt,
    const short* __restrict__ rootwT, const float* __restrict__ rootb,
    const float* __restrict__ gnlin, float* __restrict__ stats,
    const float* __restrict__ gamma, const float* __restrict__ beta,
    const short* __restrict__ gwihB, const short* __restrict__ gwhhB,
    const float* __restrict__ bih, const float* __restrict__ bhh,
    float* __restrict__ h, float* __restrict__ out,
    const int* __restrict__ batch, float* __restrict__ pooled,
    float* __restrict__ pcnt, int doPool, int layer) {
  __shared__ float msh[16*65];
  __shared__ float lgsh[16*12];
  __shared__ float ssh[16*16];
  __shared__ float igsh[640];
  __shared__ float Bsh[64];
  __shared__ __align__(16) float mrsh[16*68];
  const int tid = threadIdx.x, lane = tid & 63, wave = tid >> 6;
  const int m15 = lane & 15, kq = lane >> 4;
  const int nb = blockIdx.x * 16;
  const f32x4 zero4 = {0.f,0.f,0.f,0.f};
  const float invN = 1.f / (float)Nn;
  const int d = wave*16 + m15;   // os = wave, o16 = m15 in agg layout

  // ---- phase A: m = agg/cnt + out@rootw + rootb (into LDS only) ----
  {
    bf16x8 b0 = *(const bf16x8*)(rootwT + d*64 + kq*8);
    bf16x8 b1 = *(const bf16x8*)(rootwT + d*64 + 32 + kq*8);
    float rbv = rootb[d];
    const float* sp = out + (size_t)(nb + m15)*64 + kq*8;
    bf16x8 a0 = pack8v(*(const f32x4*)(sp),      *(const f32x4*)(sp + 4));
    bf16x8 a1 = pack8v(*(const f32x4*)(sp + 32), *(const f32x4*)(sp + 36));
    f32x4 p = __builtin_amdgcn_mfma_f32_16x16x32_bf16(a0, b0, zero4, 0, 0, 0);
    p = __builtin_amdgcn_mfma_f32_16x16x32_bf16(a1, b1, p, 0, 0, 0);
    #pragma unroll
    for (int r = 0; r < 4; ++r) {
      int ln = kq*4 + r;
      int node = nb + ln;
      size_t ai = ((size_t)wave*Nn + node)*16 + m15;
      float av = agg[ai];
      agg[ai] = 0.f;                       // re-zero for next layer (owned element)
      msh[ln*65 + d] = av / fmaxf(cnt[node], 1.f) + rbv + p[r];
    }
  }
  __syncthreads();

  // ---- phase B: logits + softmax (LDS) ----
  {
    int n = tid >> 4, g = tid & 15;
    if (g < 10) {
      float lg = 0.f;
      #pragma unroll 8
      for (int k = 0; k < 64; ++k) lg += msh[n*65 + k] * gnlin[k*10 + g];
      lgsh[n*12 + g] = lg;
    }
  }
  __syncthreads();
  {
    int n = tid >> 4, g = tid & 15;
    if (g < 10) {
      float mx = -1e30f;
      #pragma unroll
      for (int gg = 0; gg < 10; ++gg) mx = fmaxf(mx, lgsh[n*12 + gg]);
      float sum = 0.f;
      #pragma unroll
      for (int gg = 0; gg < 10; ++gg) sum += expf(lgsh[n*12 + gg] - mx);
      ssh[n*16 + g] = expf(lgsh[n*12 + g] - mx) / sum;
    }
  }
  __syncthreads();

  // ---- phase C: BN stat partials ----
  for (int c = tid; c < 640; c += 256) {
    int g = c >> 6, dd = c & 63;
    float a1 = 0.f, a2 = 0.f;
    #pragma unroll
    for (int n = 0; n < 16; ++n) {
      float t = ssh[n*16 + g] * msh[n*65 + dd];
      a1 += t; a2 += t*t;
    }
    atomicAdd(&stats[c], a1);
    atomicAdd(&stats[640 + c], a2);
  }

  // ---- grid-wide sync on stats ----
  __threadfence();        // drain this thread's atomics
  __syncthreads();        // whole block's atomics done
  if (tid == 0) {
    unsigned int* ctr = (unsigned int*)(stats + 1280) + layer;
    atomicAdd(ctr, 1u);
    int guard = 0;
    while (__hip_atomic_load(ctr, __ATOMIC_RELAXED, __HIP_MEMORY_SCOPE_AGENT) < 256u
           && guard < 1000000) {
      ++guard;
      __builtin_amdgcn_s_sleep(8);
    }
    __threadfence();
  }
  __syncthreads();

  // ---- phase D: DGN finalize + relu + GRU + residual (+pool) ----
  if (tid < 64) {
    float bacc = 0.f;
    #pragma unroll
    for (int g = 0; g < 10; ++g) {
      int c = g*64 + tid;
      float s1 = __hip_atomic_load(&stats[c],       __ATOMIC_RELAXED, __HIP_MEMORY_SCOPE_AGENT);
      float s2 = __hip_atomic_load(&stats[640 + c], __ATOMIC_RELAXED, __HIP_MEMORY_SCOPE_AGENT);
      float mu = s1 * invN;
      float var = s2 * invN - mu*mu;
      float ig = (1.0f / sqrtf(var + EPSf)) * gamma[c];
      igsh[c] = ig;
      bacc += beta[c] - mu * ig;
    }
    Bsh[tid] = bacc;
  }
  __syncthreads();

  for (int idx = tid; idx < 1024; idx += 256) {
    int n = idx >> 6, dd = idx & 63;
    float mv = msh[n*65 + dd];
    float SA = 0.f;
    #pragma unroll
    for (int g = 0; g < 10; ++g) SA += ssh[n*16 + g] * igsh[g*64 + dd];
    mrsh[n*68 + dd] = fmaxf(mv * (1.f + LAMf*SA) + LAMf*Bsh[dd], 0.f);
  }
  __syncthreads();

  bf16x8 mrf[2], hf[2];
  {
    const float* mp = mrsh + m15*68 + kq*8;
    const float* hp = h + (size_t)(nb + m15)*64 + kq*8;
    #pragma unroll
    for (int ks = 0; ks < 2; ++ks) {
      mrf[ks] = pack8v(*(const f32x4*)(mp + ks*32), *(const f32x4*)(mp + ks*32 + 4));
      hf[ks]  = pack8v(*(const f32x4*)(hp + ks*32), *(const f32x4*)(hp + ks*32 + 4));
    }
  }
  f32x4 gi[3], gh[3];
  #pragma unroll
  for (int p = 0; p < 3; ++p) {
    int j = p*64 + d;
    bf16x8 bi0 = *(const bf16x8*)(gwihB + j*64 + kq*8);
    bf16x8 bi1 = *(const bf16x8*)(gwihB + j*64 + 32 + kq*8);
    bf16x8 bh0 = *(const bf16x8*)(gwhhB + j*64 + kq*8);
    bf16x8 bh1 = *(const bf16x8*)(gwhhB + j*64 + 32 + kq*8);
    f32x4 a = __builtin_amdgcn_mfma_f32_16x16x32_bf16(mrf[0], bi0, zero4, 0, 0, 0);
    gi[p] = __builtin_amdgcn_mfma_f32_16x16x32_bf16(mrf[1], bi1, a, 0, 0, 0);
    f32x4 b = __builtin_amdgcn_mfma_f32_16x16x32_bf16(hf[0], bh0, zero4, 0, 0, 0);
    gh[p] = __builtin_amdgcn_mfma_f32_16x16x32_bf16(hf[1], bh1, b, 0, 0, 0);
  }
  float bir = bih[d],      bhr = bhh[d];
  float biz = bih[64 + d], bhz = bhh[64 + d];
  float bin = bih[128 + d], bhn = bhh[128 + d];
  __syncthreads();   // all h-fragment reads done before any h write
  #pragma unroll
  for (int r = 0; r < 4; ++r) {
    int node = nb + kq*4 + r;
    float rr = sigm(gi[0][r] + bir + gh[0][r] + bhr);
    float z  = sigm(gi[1][r] + biz + gh[1][r] + bhz);
    float nn = tanhf(gi[2][r] + bin + rr * (gh[2][r] + bhn));
    float hv = h[node*64 + d];
    float hn = (1.f - z) * nn + z * hv;
    h[node*64 + d] = hn;
    float ov = hn + out[node*64 + d];
    out[node*64 + d] = ov;
    if (doPool) {
      int b = batch[node];
      atomicAdd(&pooled[b*64 + d], ov);
      if (d == 0) atomicAdd(&pcnt[b], 1.f);
    }
  }
}

// ---------------- post FC + output ----------------
__global__ void k_final(const float* __restrict__ pooled, const float* __restrict__ pcnt,
                        const float* __restrict__ postW, const float* __restrict__ postb,
                        const float* __restrict__ outW, const float* __restrict__ outb,
                        float* __restrict__ y) {
  int b = blockIdx.x, d = threadIdx.x;
  __shared__ float pl[64];
  float c = fmaxf(pcnt[b], 1.f);
  pl[d] = pooled[b*64 + d] / c;
  __syncthreads();
  float acc = postb[d];
  #pragma unroll 8
  for (int k = 0; k < 64; ++k) acc += pl[k] * postW[k*64 + d];
  acc = fmaxf(acc, 0.f);
  float v = acc * outW[d];
  #pragma unroll
  for (int off = 32; off > 0; off >>= 1) v += __shfl_down(v, off, 64);
  if (d == 0) y[b] = v + outb[0];
}

extern "C" void kernel_launch(void* const* d_in, const int* in_sizes, int n_in,
                              void* d_out, int out_size, void* d_ws, size_t ws_size,
                              hipStream_t stream) {
  (void)in_sizes; (void)n_in; (void)out_size; (void)ws_size;
  const float* x        = (const float*)d_in[0];
  const float* edge_attr= (const float*)d_in[1];
  const float* preW     = (const float*)d_in[2];
  const float* preb     = (const float*)d_in[3];
  const float* ew1      = (const float*)d_in[4];
  const float* eb1      = (const float*)d_in[5];
  const float* ew2      = (const float*)d_in[6];
  const float* eb2      = (const float*)d_in[7];
  const float* rootw    = (const float*)d_in[8];
  const float* rootb    = (const float*)d_in[9];
  const float* gwih     = (const float*)d_in[10];
  const float* gwhh     = (const float*)d_in[11];
  const float* gbih     = (const float*)d_in[12];
  const float* gbhh     = (const float*)d_in[13];
  const float* gnlin    = (const float*)d_in[14];
  const float* gngamma  = (const float*)d_in[15];
  const float* gnbeta   = (const float*)d_in[16];
  const float* postW    = (const float*)d_in[17];
  const float* postb    = (const float*)d_in[18];
  const float* outW     = (const float*)d_in[19];
  const float* outb     = (const float*)d_in[20];
  const int*   eidx     = (const int*)d_in[21];
  const int*   batch    = (const int*)d_in[22];
  const int* src = eidx;
  const int* dst = eidx + Ee;
  float* y = (float*)d_out;

  float* ws     = (float*)d_ws;
  float* out    = ws;                     // N*64
  float* hbuf   = out    + Nn*64;
  float* mbuf   = hbuf   + Nn*64;         // unused (kept for layout stability)
  float* sbuf   = mbuf   + Nn*64;         // unused
  float* agg    = sbuf   + Nn*16;         // N*64 ([os][node][16] layout)
  float* stats  = agg    + Nn*64;         // 1280 stats + 3 sync ctrs + pad (2048)
  float* cnt    = stats  + 2048;          // N
  float* pooled = cnt    + Nn;            // N (>= B*64)
  float* pcnt   = pooled + Nn;            // 64
  float* bfbase = pcnt   + 64;
  short* w1T    = (short*)bfbase;         // 3*4096
  short* b2T    = w1T    + 3*4096;
  short* w2T    = b2T    + 3*4096;        // 3*262144
  short* rootwT = w2T    + 3*262144;      // 3*4096
  short* gwihB  = rootwT + 3*4096;        // 3*12288
  short* gwhhB  = gwihB  + 3*12288;       // 3*12288
  short* preWT  = gwhhB  + 3*12288;       // 8192

  // single memset: agg + stats(+ctrs) + cnt + pooled + pcnt (contiguous)
  hipMemsetAsync(agg, 0, (Nn*64 + 2048 + Nn + Nn + 64)*sizeof(float), stream);

  k_prep<<<337, 256, 0, stream>>>(ew1, ew2, eb2, rootw, gwih, gwhh, preW, preb,
                                  postW, postb, outW, outb, dst,
                                  w1T, b2T, w2T, rootwT, gwihB, gwhhB, preWT,
                                  cnt, y);
  k_pre<<<Nn/16, 256, 0, stream>>>(x, preWT, preb, out, hbuf);

  for (int i = 0; i < 3; ++i) {
    k_msg<<<(Ee/128)*4, 128, 0, stream>>>(out, edge_attr,
                                     w1T + i*4096, eb1 + i*64,
                                     w2T + i*262144, b2T + i*4096,
                                     src, dst, agg, stats);
    k_mgru<<<Nn/16, 256, 0, stream>>>(agg, cnt, rootwT + i*4096, rootb + i*64,
                                      gnlin + i*640, stats,
                                      gngamma + i*640, gnbeta + i*640,
                                      gwihB + i*12288, gwhhB + i*12288,
                                      gbih + i*192, gbhh + i*192, hbuf, out,
                                      batch, pooled, pcnt, (i == 2) ? 1 : 0, i);
  }

  k_final<<<Bb, 64, 0, stream>>>(pooled, pcnt, postW, postb, outW, outb, y);
}

// Round 11
// 336.630 us; speedup vs baseline: 1.1375x; 1.1375x over previous
//
#include <hip/hip_runtime.h>
#include <math.h>

#define Nn 4096
#define Ee 32768
#define Bb 64
#define FINc 128
#define Dd 64
#define SIGf 0.15f
#define LAMf 0.01f
#define EPSf 1e-5f

typedef __attribute__((ext_vector_type(8))) short bf16x8;
typedef __attribute__((ext_vector_type(4))) float f32x4;

__device__ inline short f2bf(float f) {
  union { float f; unsigned u; } v; v.f = f;
  unsigned r = v.u + 0x7fffu + ((v.u >> 16) & 1u);
  return (short)(r >> 16);
}
__device__ inline float bf2f(unsigned short s) {
  union { unsigned u; float f; } v; v.u = ((unsigned)s) << 16; return v.f;
}
__device__ inline bf16x8 pack8v(f32x4 a, f32x4 b) {
  bf16x8 r;
  r[0]=f2bf(a.x); r[1]=f2bf(a.y); r[2]=f2bf(a.z); r[3]=f2bf(a.w);
  r[4]=f2bf(b.x); r[5]=f2bf(b.y); r[6]=f2bf(b.z); r[7]=f2bf(b.w);
  return r;
}
__device__ inline float sigm(float x) { return 1.f / (1.f + expf(-x)); }

// async global->LDS, 16B/lane; lds dest is wave-uniform base + lane*16 (linear)
__device__ inline void stage16(const void* g, void* l) {
  __builtin_amdgcn_global_load_lds(
      (const __attribute__((address_space(1))) void*)g,
      (__attribute__((address_space(3))) void*)l, 16, 0, 0);
}

// ---------------- prep: w2 LDS-tiled transpose + small packs + in-degree + tkl ----------------
__global__ __launch_bounds__(256) void k_prep(
    const float* __restrict__ w1, const float* __restrict__ w2,
    const float* __restrict__ b2, const float* __restrict__ rootw,
    const float* __restrict__ gwih, const float* __restrict__ gwhh,
    const float* __restrict__ preW, const float* __restrict__ preb,
    const float* __restrict__ postW, const float* __restrict__ postb,
    const float* __restrict__ outW, const float* __restrict__ outb,
    const int* __restrict__ dstIdx,
    short* __restrict__ w1T, short* __restrict__ b2T,
    short* __restrict__ w2T, short* __restrict__ rootwT,
    short* __restrict__ gwihB, short* __restrict__ gwhhB,
    short* __restrict__ preWT, float* __restrict__ cnt,
    float* __restrict__ y) {
  const int tid = threadIdx.x;
  const int bid = blockIdx.x;
  __shared__ float tile[64][65];
  __shared__ float red[256];

  if (bid < 192) {
    // transpose one 64x64 page: w2T[l][h][o][f] = w2[l][h][f][o]
    const float* srcp = w2 + (size_t)bid*4096;
    #pragma unroll
    for (int r = 0; r < 16; ++r) {
      int i2 = r*256 + tid;
      tile[i2 >> 6][i2 & 63] = srcp[i2];
    }
    __syncthreads();
    short* dstp = w2T + (size_t)bid*4096;
    #pragma unroll
    for (int r = 0; r < 16; ++r) {
      int i2 = r*256 + tid;
      dstp[i2] = f2bf(tile[i2 & 63][i2 >> 6]);
    }
  } else if (bid < 336) {
    int idx = (bid - 192)*256 + tid;
    if (idx < 3*64*64) {
      int f = idx & 63, h = (idx >> 6) & 63, l = idx >> 12;
      w1T[idx] = f2bf(w1[l*4096 + f*64 + h]);          // w1T[l][h][f]
      b2T[idx] = f2bf(b2[l*4096 + f*64 + h]);          // b2T[l][o][f]
      rootwT[idx] = f2bf(rootw[l*4096 + f*64 + h]);    // rootwT[l][d][k]
    }
    if (idx < 3*192*64) {
      gwihB[idx] = f2bf(gwih[idx]);
      gwhhB[idx] = f2bf(gwhh[idx]);
    }
    if (idx < 64*128) {
      int k = idx & 127, d = idx >> 7;
      preWT[idx] = f2bf(preW[k*64 + d]);               // preWT[d][k]
    }
    if (idx < Ee) atomicAdd(&cnt[dstIdx[idx]], 1.0f);
  } else {
    const float logc = logf(SIGf * sqrtf(6.28318530717958647692f));
    const float c2 = 0.5f / (SIGf * SIGf);
    float acc = 0.f;
    for (int i = tid; i < FINc*Dd; i += 256) { float w = preW[i];  acc += c2*w*w + logc; }
    for (int i = tid; i < Dd; i += 256)      { float w = preb[i];  acc += c2*w*w + logc; }
    for (int i = tid; i < Dd*Dd; i += 256)   { float w = postW[i]; acc += c2*w*w + logc; }
    for (int i = tid; i < Dd; i += 256)      { float w = postb[i]; acc += c2*w*w + logc; }
    for (int i = tid; i < Dd; i += 256)      { float w = outW[i];  acc += c2*w*w + logc; }
    if (tid == 0)                            { float w = outb[0];  acc += c2*w*w + logc; }
    red[tid] = acc; __syncthreads();
    for (int s = 128; s > 0; s >>= 1) { if (tid < s) red[tid] += red[tid+s]; __syncthreads(); }
    if (tid == 0) y[Bb] = red[0];
  }
}

// ---------------- pre FC + relu via MFMA ----------------
__global__ __launch_bounds__(256) void k_pre(const float* __restrict__ x,
                                             const short* __restrict__ preWT,
                                             const float* __restrict__ preb,
                                             float* __restrict__ out, float* __restrict__ h) {
  const int tid = threadIdx.x, lane = tid & 63, wave = tid >> 6;
  const int m15 = lane & 15, kq = lane >> 4;
  const int nb = blockIdx.x * 16;
  const f32x4 zero4 = {0.f,0.f,0.f,0.f};
  const int d = wave*16 + m15;
  bf16x8 bfr[4];
  #pragma unroll
  for (int c = 0; c < 4; ++c)
    bfr[c] = *(const bf16x8*)(preWT + d*128 + c*32 + kq*8);
  const float* xp = x + (size_t)(nb + m15)*128 + kq*8;
  f32x4 p = zero4;
  #pragma unroll
  for (int c = 0; c < 4; ++c) {
    bf16x8 a = pack8v(*(const f32x4*)(xp + c*32), *(const f32x4*)(xp + c*32 + 4));
    p = __builtin_amdgcn_mfma_f32_16x16x32_bf16(a, bfr[c], p, 0, 0, 0);
  }
  float bv = preb[d];
  #pragma unroll
  for (int r = 0; r < 4; ++r) {
    int node = nb + kq*4 + r;
    float v = fmaxf(p[r] + bv, 0.f);
    out[node*64 + d] = v;
    h[node*64 + d] = v;
  }
}

// ---------------- fused edge-MLP + bilinear message GEMM (MFMA) + scatter ----------------
// Round-8 structure (128 edges x 16 o, 2 waves, grid 1024) with w2 staging via
// global_load_lds (dbuf): linear LDS dest + swizzle folded into per-lane GLOBAL
// source (rule 21; LDS[x] = G[x ^ swz(x)] — identical layout to round 8, reads
// unchanged). Removes 8 ds_write_b128/lane/chunk, halves barriers (18->10),
// frees ~32 staging VGPRs. LDS 51KB -> 3 blocks/CU.
__global__ __launch_bounds__(128) void k_msg(
    const float* __restrict__ out, const float* __restrict__ edge_attr,
    const short* __restrict__ w1T, const float* __restrict__ b1,
    const short* __restrict__ w2T, const short* __restrict__ b2T,
    const int* __restrict__ src, const int* __restrict__ dst,
    float* __restrict__ agg, float* __restrict__ stats) {
  __shared__ short hidT[64*136];
  __shared__ __align__(16) short wstage[2][8192];   // dbuf: 8 slices x 2KB each
  __shared__ int srcv[128];
  __shared__ int dstv[128];

  const int tid  = threadIdx.x;
  const int lane = tid & 63;
  const int w    = tid >> 6;
  const int m15  = lane & 15;
  const int kq   = lane >> 4;
  const int ebi  = blockIdx.x & 255;
  const int os   = blockIdx.x >> 8;
  const int ebase = ebi * 128;
  const int we   = w*64;

  srcv[tid] = src[ebase + tid];
  dstv[tid] = dst[ebase + tid];
  if (blockIdx.x == 0) {
    for (int i = tid; i < 1280; i += 128) stats[i] = 0.f;
  }
  __syncthreads();

  const f32x4 zero4 = {0.f, 0.f, 0.f, 0.f};

  // per-lane swizzled source offset (bytes) for linear dest byte lane*16:
  // swz(x) = (((x>>7)&7)<<4); involution, bits 7-9 untouched by XOR.
  const int soff = (lane*16) ^ (((lane >> 3) & 7) << 4);
  // wave w stages slices w*4..w*4+3 (2KB each = 2 gll calls of 1KB)
  const char* gwbase = (const char*)w2T + (size_t)(w*4)*8192 + (size_t)os*2048 + soff;

  // ---- issue chunk 0 into buf 0 (overlaps gather + MLP) ----
  {
    char* lb = (char*)&wstage[0][w*4*1024];
    #pragma unroll
    for (int j2 = 0; j2 < 4; ++j2) {
      stage16(gwbase + (size_t)j2*8192,        lb + j2*2048);
      stage16(gwbase + (size_t)j2*8192 + 1024, lb + j2*2048 + 1024);
    }
  }

  // ---- gather source-node features (64 edges/wave) ----
  bf16x8 sfrag[4][2];
  #pragma unroll
  for (int t = 0; t < 4; ++t) {
    int node = srcv[we + t*16 + m15];
    const float* sp = out + node*64 + kq*8;
    #pragma unroll
    for (int ks = 0; ks < 2; ++ks)
      sfrag[t][ks] = pack8v(*(const f32x4*)(sp + ks*32), *(const f32x4*)(sp + ks*32 + 4));
  }

  // ---- edge MLP: 64 edges/wave x 64 h -> hidT[h][edge] bf16 ----
  {
    bf16x8 ea[4][2];
    #pragma unroll
    for (int t = 0; t < 4; ++t) {
      const float* ep = edge_attr + (size_t)(ebase + we + t*16 + m15)*64 + kq*8;
      ea[t][0] = pack8v(*(const f32x4*)(ep),      *(const f32x4*)(ep + 4));
      ea[t][1] = pack8v(*(const f32x4*)(ep + 32), *(const f32x4*)(ep + 36));
    }
    #pragma unroll
    for (int hg = 0; hg < 4; ++hg) {
      const short* wp = w1T + (hg*16 + m15)*64 + kq*8;
      bf16x8 bw0 = *(const bf16x8*)(wp);
      bf16x8 bw1 = *(const bf16x8*)(wp + 32);
      float b1v = b1[hg*16 + m15];
      #pragma unroll
      for (int t = 0; t < 4; ++t) {
        f32x4 p = __builtin_amdgcn_mfma_f32_16x16x32_bf16(ea[t][0], bw0, zero4, 0, 0, 0);
        p = __builtin_amdgcn_mfma_f32_16x16x32_bf16(ea[t][1], bw1, p, 0, 0, 0);
        ushort4 hp4;
        hp4.x = (unsigned short)f2bf(fmaxf(p.x + b1v, 0.f));
        hp4.y = (unsigned short)f2bf(fmaxf(p.y + b1v, 0.f));
        hp4.z = (unsigned short)f2bf(fmaxf(p.z + b1v, 0.f));
        hp4.w = (unsigned short)f2bf(fmaxf(p.w + b1v, 0.f));
        *(ushort4*)(hidT + (hg*16 + m15)*136 + we + t*16 + kq*4) = hp4;
      }
    }
  }
  __syncthreads();   // hidT ready; chunk-0 gll drained (implicit vmcnt(0))

  // ---- bilinear over h, w2 from LDS, dbuf chunks of 8 pages ----
  f32x4 acc[4] = {zero4, zero4, zero4, zero4};
  const int ro0 = (m15*128 + kq*16) ^ ((m15 & 7) << 4);
  const int ro1 = (m15*128 + 64 + kq*16) ^ ((m15 & 7) << 4);

  for (int c = 0; c < 8; ++c) {
    if (c < 7) {   // issue next chunk into other buffer; hides under compute
      const char* gn = gwbase + (size_t)(c + 1)*65536;
      char* lb = (char*)&wstage[(c + 1) & 1][w*4*1024];
      #pragma unroll
      for (int j2 = 0; j2 < 4; ++j2) {
        stage16(gn + (size_t)j2*8192,        lb + j2*2048);
        stage16(gn + (size_t)j2*8192 + 1024, lb + j2*2048 + 1024);
      }
    }
    #pragma unroll 2
    for (int j = 0; j < 8; ++j) {
      const char* wbp = (const char*)&wstage[c & 1][0] + j*2048;
      bf16x8 W0 = *(const bf16x8*)(wbp + ro0);
      bf16x8 W1 = *(const bf16x8*)(wbp + ro1);
      const unsigned short* hrow =
          (const unsigned short*)hidT + (c*8 + j)*136 + we + kq*4;
      #pragma unroll
      for (int t = 0; t < 4; ++t) {
        f32x4 p = __builtin_amdgcn_mfma_f32_16x16x32_bf16(sfrag[t][0], W0, zero4, 0, 0, 0);
        p = __builtin_amdgcn_mfma_f32_16x16x32_bf16(sfrag[t][1], W1, p, 0, 0, 0);
        ushort4 hu = *(const ushort4*)(hrow + t*16);
        acc[t].x += bf2f(hu.x) * p.x;
        acc[t].y += bf2f(hu.y) * p.y;
        acc[t].z += bf2f(hu.z) * p.z;
        acc[t].w += bf2f(hu.w) * p.w;
      }
    }
    __syncthreads();   // drains next-chunk gll; compute reads of buf[c&1] done
  }

  // ---- bias term ----
  {
    const short* Bp = b2T + (os*16 + m15)*64 + kq*8;
    bf16x8 W0 = *(const bf16x8*)(Bp);
    bf16x8 W1 = *(const bf16x8*)(Bp + 32);
    #pragma unroll
    for (int t = 0; t < 4; ++t) {
      f32x4 p = __builtin_amdgcn_mfma_f32_16x16x32_bf16(sfrag[t][0], W0, zero4, 0, 0, 0);
      p = __builtin_amdgcn_mfma_f32_16x16x32_bf16(sfrag[t][1], W1, p, 0, 0, 0);
      acc[t] += p;
    }
  }

  // ---- scatter: agg[os][node][o16]; 16 lanes = one 64B segment ----
  #pragma unroll
  for (int t = 0; t < 4; ++t) {
    #pragma unroll
    for (int r = 0; r < 4; ++r) {
      int e = we + t*16 + kq*4 + r;
      atomicAdd(&agg[((size_t)os*Nn + dstv[e])*16 + m15], acc[t][r]);
    }
  }
}

// ---------------- fused: m = agg/cnt + out@rootw + rootb ; softmax ; BN stats ----------------
__global__ __launch_bounds__(256) void k_m_fused(
    float* __restrict__ agg, const float* __restrict__ cnt,
    const float* __restrict__ out, const short* __restrict__ rootwT,
    const float* __restrict__ rootb, const float* __restrict__ gnlin,
    float* __restrict__ m, float* __restrict__ sbuf, float* __restrict__ stats) {
  __shared__ float msh[16*65];
  __shared__ float lgsh[16*12];
  __shared__ float ssh[16*16];
  const int tid = threadIdx.x, lane = tid & 63, wave = tid >> 6;
  const int m15 = lane & 15, kq = lane >> 4;
  const int nb = blockIdx.x * 16;
  const f32x4 zero4 = {0.f,0.f,0.f,0.f};
  const int d = wave*16 + m15;   // os = wave, o16 = m15 in agg layout

  bf16x8 b0 = *(const bf16x8*)(rootwT + d*64 + kq*8);
  bf16x8 b1 = *(const bf16x8*)(rootwT + d*64 + 32 + kq*8);
  float rbv = rootb[d];
  {
    const float* sp = out + (size_t)(nb + m15)*64 + kq*8;
    bf16x8 a0 = pack8v(*(const f32x4*)(sp),      *(const f32x4*)(sp + 4));
    bf16x8 a1 = pack8v(*(const f32x4*)(sp + 32), *(const f32x4*)(sp + 36));
    f32x4 p = __builtin_amdgcn_mfma_f32_16x16x32_bf16(a0, b0, zero4, 0, 0, 0);
    p = __builtin_amdgcn_mfma_f32_16x16x32_bf16(a1, b1, p, 0, 0, 0);
    #pragma unroll
    for (int r = 0; r < 4; ++r) {
      int ln = kq*4 + r;
      int node = nb + ln;
      size_t ai = ((size_t)wave*Nn + node)*16 + m15;
      float av = agg[ai];
      agg[ai] = 0.f;
      float mv = av / fmaxf(cnt[node], 1.f) + rbv + p[r];
      m[node*64 + d] = mv;
      msh[ln*65 + d] = mv;
    }
  }
  __syncthreads();

  // logits: 16 nodes x 10 groups
  {
    int n = tid >> 4, g = tid & 15;
    if (g < 10) {
      float lg = 0.f;
      #pragma unroll 8
      for (int k = 0; k < 64; ++k) lg += msh[n*65 + k] * gnlin[k*10 + g];
      lgsh[n*12 + g] = lg;
    }
  }
  __syncthreads();
  // softmax
  {
    int n = tid >> 4, g = tid & 15;
    if (g < 10) {
      float mx = -1e30f;
      #pragma unroll
      for (int gg = 0; gg < 10; ++gg) mx = fmaxf(mx, lgsh[n*12 + gg]);
      float sum = 0.f;
      #pragma unroll
      for (int gg = 0; gg < 10; ++gg) sum += expf(lgsh[n*12 + gg] - mx);
      float sv = expf(lgsh[n*12 + g] - mx) / sum;
      sbuf[(nb + n)*16 + g] = sv;
      ssh[n*16 + g] = sv;
    }
  }
  __syncthreads();
  // BN stat partials over this block's 16 nodes
  for (int c = tid; c < 640; c += 256) {
    int g = c >> 6, dd = c & 63;
    float a1 = 0.f, a2 = 0.f;
    #pragma unroll
    for (int n = 0; n < 16; ++n) {
      float t = ssh[n*16 + g] * msh[n*65 + dd];
      a1 += t; a2 += t*t;
    }
    atomicAdd(&stats[c], a1);
    atomicAdd(&stats[640 + c], a2);
  }
}

// ---------------- fused DGN-finalize + relu + GRU (MFMA) + residual (+pool on last layer) ----------------
__global__ __launch_bounds__(256) void k_gru(
    const float* __restrict__ m, const float* __restrict__ sbuf,
    const float* __restrict__ stats, const float* __restrict__ gamma,
    const float* __restrict__ beta, const short* __restrict__ gwihB,
    const short* __restrict__ gwhhB, const float* __restrict__ bih,
    const float* __restrict__ bhh, float* __restrict__ h,
    float* __restrict__ out,
    const int* __restrict__ batch, float* __restrict__ pooled,
    float* __restrict__ pcnt, int doPool) {
  __shared__ __align__(16) float mrsh[16*68];
  __shared__ float igsh[640];
  __shared__ float Bsh[64];
  __shared__ float ssh[256];
  const int tid = threadIdx.x, lane = tid & 63, wave = tid >> 6;
  const int m15 = lane & 15, kq = lane >> 4;
  const int nb = blockIdx.x * 16;
  const f32x4 zero4 = {0.f,0.f,0.f,0.f};
  const float invN = 1.f / (float)Nn;

  if (tid < 64) {
    float bacc = 0.f;
    #pragma unroll
    for (int g = 0; g < 10; ++g) {
      int c = g*64 + tid;
      float mu = stats[c] * invN;
      float var = stats[640 + c] * invN - mu*mu;
      float ig = (1.0f / sqrtf(var + EPSf)) * gamma[c];
      igsh[c] = ig;
      bacc += beta[c] - mu * ig;
    }
    Bsh[tid] = bacc;
  }
  ssh[tid] = sbuf[nb*16 + tid];
  __syncthreads();

  for (int idx = tid; idx < 1024; idx += 256) {
    int n = idx >> 6, dd = idx & 63;
    float mv = m[(nb + n)*64 + dd];
    float SA = 0.f;
    #pragma unroll
    for (int g = 0; g < 10; ++g) SA += ssh[n*16 + g] * igsh[g*64 + dd];
    mrsh[n*68 + dd] = fmaxf(mv * (1.f + LAMf*SA) + LAMf*Bsh[dd], 0.f);
  }
  __syncthreads();

  // fragments (single 16-node tile)
  bf16x8 mrf[2], hf[2];
  {
    const float* mp = mrsh + m15*68 + kq*8;
    const float* hp = h + (size_t)(nb + m15)*64 + kq*8;
    #pragma unroll
    for (int ks = 0; ks < 2; ++ks) {
      mrf[ks] = pack8v(*(const f32x4*)(mp + ks*32), *(const f32x4*)(mp + ks*32 + 4));
      hf[ks]  = pack8v(*(const f32x4*)(hp + ks*32), *(const f32x4*)(hp + ks*32 + 4));
    }
  }
  const int d = wave*16 + m15;
  f32x4 gi[3], gh[3];
  #pragma unroll
  for (int p = 0; p < 3; ++p) {
    int j = p*64 + d;
    bf16x8 bi0 = *(const bf16x8*)(gwihB + j*64 + kq*8);
    bf16x8 bi1 = *(const bf16x8*)(gwihB + j*64 + 32 + kq*8);
    bf16x8 bh0 = *(const bf16x8*)(gwhhB + j*64 + kq*8);
    bf16x8 bh1 = *(const bf16x8*)(gwhhB + j*64 + 32 + kq*8);
    f32x4 a = __builtin_amdgcn_mfma_f32_16x16x32_bf16(mrf[0], bi0, zero4, 0, 0, 0);
    gi[p] = __builtin_amdgcn_mfma_f32_16x16x32_bf16(mrf[1], bi1, a, 0, 0, 0);
    f32x4 b = __builtin_amdgcn_mfma_f32_16x16x32_bf16(hf[0], bh0, zero4, 0, 0, 0);
    gh[p] = __builtin_amdgcn_mfma_f32_16x16x32_bf16(hf[1], bh1, b, 0, 0, 0);
  }
  float bir = bih[d],      bhr = bhh[d];
  float biz = bih[64 + d], bhz = bhh[64 + d];
  float bin = bih[128 + d], bhn = bhh[128 + d];
  __syncthreads();   // all h-fragment reads done before any h write
  #pragma unroll
  for (int r = 0; r < 4; ++r) {
    int node = nb + kq*4 + r;
    float rr = sigm(gi[0][r] + bir + gh[0][r] + bhr);
    float z  = sigm(gi[1][r] + biz + gh[1][r] + bhz);
    float nn = tanhf(gi[2][r] + bin + rr * (gh[2][r] + bhn));
    float hv = h[node*64 + d];
    float hn = (1.f - z) * nn + z * hv;
    h[node*64 + d] = hn;
    float ov = hn + out[node*64 + d];
    out[node*64 + d] = ov;
    if (doPool) {
      int b = batch[node];
      atomicAdd(&pooled[b*64 + d], ov);
      if (d == 0) atomicAdd(&pcnt[b], 1.f);
    }
  }
}

// ---------------- post FC + output ----------------
__global__ void k_final(const float* __restrict__ pooled, const float* __restrict__ pcnt,
                        const float* __restrict__ postW, const float* __restrict__ postb,
                        const float* __restrict__ outW, const float* __restrict__ outb,
                        float* __restrict__ y) {
  int b = blockIdx.x, d = threadIdx.x;
  __shared__ float pl[64];
  float c = fmaxf(pcnt[b], 1.f);
  pl[d] = pooled[b*64 + d] / c;
  __syncthreads();
  float acc = postb[d];
  #pragma unroll 8
  for (int k = 0; k < 64; ++k) acc += pl[k] * postW[k*64 + d];
  acc = fmaxf(acc, 0.f);
  float v = acc * outW[d];
  #pragma unroll
  for (int off = 32; off > 0; off >>= 1) v += __shfl_down(v, off, 64);
  if (d == 0) y[b] = v + outb[0];
}

extern "C" void kernel_launch(void* const* d_in, const int* in_sizes, int n_in,
                              void* d_out, int out_size, void* d_ws, size_t ws_size,
                              hipStream_t stream) {
  (void)in_sizes; (void)n_in; (void)out_size; (void)ws_size;
  const float* x        = (const float*)d_in[0];
  const float* edge_attr= (const float*)d_in[1];
  const float* preW     = (const float*)d_in[2];
  const float* preb     = (const float*)d_in[3];
  const float* ew1      = (const float*)d_in[4];
  const float* eb1      = (const float*)d_in[5];
  const float* ew2      = (const float*)d_in[6];
  const float* eb2      = (const float*)d_in[7];
  const float* rootw    = (const float*)d_in[8];
  const float* rootb    = (const float*)d_in[9];
  const float* gwih     = (const float*)d_in[10];
  const float* gwhh     = (const float*)d_in[11];
  const float* gbih     = (const float*)d_in[12];
  const float* gbhh     = (const float*)d_in[13];
  const float* gnlin    = (const float*)d_in[14];
  const float* gngamma  = (const float*)d_in[15];
  const float* gnbeta   = (const float*)d_in[16];
  const float* postW    = (const float*)d_in[17];
  const float* postb    = (const float*)d_in[18];
  const float* outW     = (const float*)d_in[19];
  const float* outb     = (const float*)d_in[20];
  const int*   eidx     = (const int*)d_in[21];
  const int*   batch    = (const int*)d_in[22];
  const int* src = eidx;
  const int* dst = eidx + Ee;
  float* y = (float*)d_out;

  float* ws     = (float*)d_ws;
  float* out    = ws;                     // N*64
  float* hbuf   = out    + Nn*64;
  float* mbuf   = hbuf   + Nn*64;
  float* sbuf   = mbuf   + Nn*64;         // N*16
  float* agg    = sbuf   + Nn*16;         // N*64 ([os][node][16] layout)
  float* stats  = agg    + Nn*64;         // 2048
  float* cnt    = stats  + 2048;          // N
  float* pooled = cnt    + Nn;            // N (>= B*64)
  float* pcnt   = pooled + Nn;            // 64
  float* bfbase = pcnt   + 64;
  short* w1T    = (short*)bfbase;         // 3*4096
  short* b2T    = w1T    + 3*4096;
  short* w2T    = b2T    + 3*4096;        // 3*262144
  short* rootwT = w2T    + 3*262144;      // 3*4096
  short* gwihB  = rootwT + 3*4096;        // 3*12288
  short* gwhhB  = gwihB  + 3*12288;       // 3*12288
  short* preWT  = gwhhB  + 3*12288;       // 8192

  // single memset: agg + stats + cnt + pooled + pcnt (contiguous)
  hipMemsetAsync(agg, 0, (Nn*64 + 2048 + Nn + Nn + 64)*sizeof(float), stream);

  k_prep<<<337, 256, 0, stream>>>(ew1, ew2, eb2, rootw, gwih, gwhh, preW, preb,
                                  postW, postb, outW, outb, dst,
                                  w1T, b2T, w2T, rootwT, gwihB, gwhhB, preWT,
                                  cnt, y);
  k_pre<<<Nn/16, 256, 0, stream>>>(x, preWT, preb, out, hbuf);

  for (int i = 0; i < 3; ++i) {
    k_msg<<<(Ee/128)*4, 128, 0, stream>>>(out, edge_attr,
                                     w1T + i*4096, eb1 + i*64,
                                     w2T + i*262144, b2T + i*4096,
                                     src, dst, agg, stats);
    k_m_fused<<<Nn/16, 256, 0, stream>>>(agg, cnt, out, rootwT + i*4096,
                                         rootb + i*64, gnlin + i*640, mbuf, sbuf, stats);
    k_gru<<<Nn/16, 256, 0, stream>>>(mbuf, sbuf, stats, gngamma + i*640, gnbeta + i*640,
                                     gwihB + i*12288, gwhhB + i*12288,
                                     gbih + i*192, gbhh + i*192, hbuf, out,
                                     batch, pooled, pcnt, (i == 2) ? 1 : 0);
  }

  k_final<<<Bb, 64, 0, stream>>>(pooled, pcnt, postW, postb, outW, outb, y);
}

// Round 12
// 307.622 us; speedup vs baseline: 1.2448x; 1.0943x over previous
//
#include <hip/hip_runtime.h>
#include <math.h>

#define Nn 4096
#define Ee 32768
#define Bb 64
#define FINc 128
#define Dd 64
#define SIGf 0.15f
#define LAMf 0.01f
#define EPSf 1e-5f

typedef __attribute__((ext_vector_type(8))) short bf16x8;
typedef __attribute__((ext_vector_type(4))) float f32x4;

__device__ inline short f2bf(float f) {
  union { float f; unsigned u; } v; v.f = f;
  unsigned r = v.u + 0x7fffu + ((v.u >> 16) & 1u);
  return (short)(r >> 16);
}
__device__ inline float bf2f(unsigned short s) {
  union { unsigned u; float f; } v; v.u = ((unsigned)s) << 16; return v.f;
}
__device__ inline bf16x8 pack8v(f32x4 a, f32x4 b) {
  bf16x8 r;
  r[0]=f2bf(a.x); r[1]=f2bf(a.y); r[2]=f2bf(a.z); r[3]=f2bf(a.w);
  r[4]=f2bf(b.x); r[5]=f2bf(b.y); r[6]=f2bf(b.z); r[7]=f2bf(b.w);
  return r;
}
__device__ inline float sigm(float x) { return 1.f / (1.f + expf(-x)); }

// ---------------- prep: w2 LDS-tiled transpose + small packs + in-degree + tkl ----------------
__global__ __launch_bounds__(256) void k_prep(
    const float* __restrict__ w1, const float* __restrict__ w2,
    const float* __restrict__ b2, const float* __restrict__ rootw,
    const float* __restrict__ gwih, const float* __restrict__ gwhh,
    const float* __restrict__ preW, const float* __restrict__ preb,
    const float* __restrict__ postW, const float* __restrict__ postb,
    const float* __restrict__ outW, const float* __restrict__ outb,
    const int* __restrict__ dstIdx,
    short* __restrict__ w1T, short* __restrict__ b2T,
    short* __restrict__ w2T, short* __restrict__ rootwT,
    short* __restrict__ gwihB, short* __restrict__ gwhhB,
    short* __restrict__ preWT, float* __restrict__ cnt,
    float* __restrict__ y) {
  const int tid = threadIdx.x;
  const int bid = blockIdx.x;
  __shared__ float tile[64][65];
  __shared__ float red[256];

  if (bid < 192) {
    // transpose one 64x64 page: w2T[l][h][o][f] = w2[l][h][f][o]
    const float* srcp = w2 + (size_t)bid*4096;
    #pragma unroll
    for (int r = 0; r < 16; ++r) {
      int i2 = r*256 + tid;
      tile[i2 >> 6][i2 & 63] = srcp[i2];
    }
    __syncthreads();
    short* dstp = w2T + (size_t)bid*4096;
    #pragma unroll
    for (int r = 0; r < 16; ++r) {
      int i2 = r*256 + tid;
      dstp[i2] = f2bf(tile[i2 & 63][i2 >> 6]);
    }
  } else if (bid < 336) {
    int idx = (bid - 192)*256 + tid;
    if (idx < 3*64*64) {
      int f = idx & 63, h = (idx >> 6) & 63, l = idx >> 12;
      w1T[idx] = f2bf(w1[l*4096 + f*64 + h]);          // w1T[l][h][f]
      b2T[idx] = f2bf(b2[l*4096 + f*64 + h]);          // b2T[l][o][f]
      rootwT[idx] = f2bf(rootw[l*4096 + f*64 + h]);    // rootwT[l][d][k]
    }
    if (idx < 3*192*64) {
      gwihB[idx] = f2bf(gwih[idx]);
      gwhhB[idx] = f2bf(gwhh[idx]);
    }
    if (idx < 64*128) {
      int k = idx & 127, d = idx >> 7;
      preWT[idx] = f2bf(preW[k*64 + d]);               // preWT[d][k]
    }
    if (idx < Ee) atomicAdd(&cnt[dstIdx[idx]], 1.0f);
  } else {
    const float logc = logf(SIGf * sqrtf(6.28318530717958647692f));
    const float c2 = 0.5f / (SIGf * SIGf);
    float acc = 0.f;
    for (int i = tid; i < FINc*Dd; i += 256) { float w = preW[i];  acc += c2*w*w + logc; }
    for (int i = tid; i < Dd; i += 256)      { float w = preb[i];  acc += c2*w*w + logc; }
    for (int i = tid; i < Dd*Dd; i += 256)   { float w = postW[i]; acc += c2*w*w + logc; }
    for (int i = tid; i < Dd; i += 256)      { float w = postb[i]; acc += c2*w*w + logc; }
    for (int i = tid; i < Dd; i += 256)      { float w = outW[i];  acc += c2*w*w + logc; }
    if (tid == 0)                            { float w = outb[0];  acc += c2*w*w + logc; }
    red[tid] = acc; __syncthreads();
    for (int s = 128; s > 0; s >>= 1) { if (tid < s) red[tid] += red[tid+s]; __syncthreads(); }
    if (tid == 0) y[Bb] = red[0];
  }
}

// ---------------- pre FC + relu via MFMA ----------------
__global__ __launch_bounds__(256) void k_pre(const float* __restrict__ x,
                                             const short* __restrict__ preWT,
                                             const float* __restrict__ preb,
                                             float* __restrict__ out, float* __restrict__ h) {
  const int tid = threadIdx.x, lane = tid & 63, wave = tid >> 6;
  const int m15 = lane & 15, kq = lane >> 4;
  const int nb = blockIdx.x * 16;
  const f32x4 zero4 = {0.f,0.f,0.f,0.f};
  const int d = wave*16 + m15;
  bf16x8 bfr[4];
  #pragma unroll
  for (int c = 0; c < 4; ++c)
    bfr[c] = *(const bf16x8*)(preWT + d*128 + c*32 + kq*8);
  const float* xp = x + (size_t)(nb + m15)*128 + kq*8;
  f32x4 p = zero4;
  #pragma unroll
  for (int c = 0; c < 4; ++c) {
    bf16x8 a = pack8v(*(const f32x4*)(xp + c*32), *(const f32x4*)(xp + c*32 + 4));
    p = __builtin_amdgcn_mfma_f32_16x16x32_bf16(a, bfr[c], p, 0, 0, 0);
  }
  float bv = preb[d];
  #pragma unroll
  for (int r = 0; r < 4; ++r) {
    int node = nb + kq*4 + r;
    float v = fmaxf(p[r] + bv, 0.f);
    out[node*64 + d] = v;
    h[node*64 + d] = v;
  }
}

// ---------------- fused edge-MLP + bilinear message GEMM (MFMA) + scatter ----------------
// 128 edges x 16 o-values per block, 2 waves; grid = 256 ebi x 4 os = 1024
// -> 4 independent blocks/CU, small barrier domains, reg-staged w2 through
// LDS with XOR swizzle (vmcnt wait lands at next ds_write, a full compute
// phase after issue -> latency hidden). Clean per-(node,o)-once 64B atomic
// segments. [Round-8 verified structure; gll variant (r11) and h-split (r4/5)
// both regressed — see session journal.]
__global__ __launch_bounds__(128) void k_msg(
    const float* __restrict__ out, const float* __restrict__ edge_attr,
    const short* __restrict__ w1T, const float* __restrict__ b1,
    const short* __restrict__ w2T, const short* __restrict__ b2T,
    const int* __restrict__ src, const int* __restrict__ dst,
    float* __restrict__ agg, float* __restrict__ stats) {
  __shared__ short hidT[64*136];
  __shared__ __align__(16) short wstage[8192];
  __shared__ int srcv[128];
  __shared__ int dstv[128];

  const int tid  = threadIdx.x;
  const int lane = tid & 63;
  const int w    = tid >> 6;
  const int m15  = lane & 15;
  const int kq   = lane >> 4;
  const int ebi  = blockIdx.x & 255;
  const int os   = blockIdx.x >> 8;
  const int ebase = ebi * 128;
  const int we   = w*64;

  srcv[tid] = src[ebase + tid];
  dstv[tid] = dst[ebase + tid];
  if (blockIdx.x == 0) {
    for (int i = tid; i < 1280; i += 128) stats[i] = 0.f;
  }
  __syncthreads();

  const f32x4 zero4 = {0.f, 0.f, 0.f, 0.f};

  f32x4 s0, s1, s2, s3, s4, s5, s6, s7;
  {
    const short* pg = w2T + (size_t)(w*4)*4096 + os*1024 + lane*16;
    s0 = *(const f32x4*)(pg);          s1 = *(const f32x4*)(pg + 8);
    s2 = *(const f32x4*)(pg + 4096);   s3 = *(const f32x4*)(pg + 4104);
    s4 = *(const f32x4*)(pg + 8192);   s5 = *(const f32x4*)(pg + 8200);
    s6 = *(const f32x4*)(pg + 12288);  s7 = *(const f32x4*)(pg + 12296);
  }
  const int wb0 = (lane*32) ^ ((((lane*32) >> 7) & 7) << 4);
  const int wb1 = (lane*32 + 16) ^ ((((lane*32) >> 7) & 7) << 4);

  bf16x8 sfrag[4][2];
  #pragma unroll
  for (int t = 0; t < 4; ++t) {
    int node = srcv[we + t*16 + m15];
    const float* sp = out + node*64 + kq*8;
    #pragma unroll
    for (int ks = 0; ks < 2; ++ks)
      sfrag[t][ks] = pack8v(*(const f32x4*)(sp + ks*32), *(const f32x4*)(sp + ks*32 + 4));
  }

  {
    bf16x8 ea[4][2];
    #pragma unroll
    for (int t = 0; t < 4; ++t) {
      const float* ep = edge_attr + (size_t)(ebase + we + t*16 + m15)*64 + kq*8;
      ea[t][0] = pack8v(*(const f32x4*)(ep),      *(const f32x4*)(ep + 4));
      ea[t][1] = pack8v(*(const f32x4*)(ep + 32), *(const f32x4*)(ep + 36));
    }
    #pragma unroll
    for (int hg = 0; hg < 4; ++hg) {
      const short* wp = w1T + (hg*16 + m15)*64 + kq*8;
      bf16x8 bw0 = *(const bf16x8*)(wp);
      bf16x8 bw1 = *(const bf16x8*)(wp + 32);
      float b1v = b1[hg*16 + m15];
      #pragma unroll
      for (int t = 0; t < 4; ++t) {
        f32x4 p = __builtin_amdgcn_mfma_f32_16x16x32_bf16(ea[t][0], bw0, zero4, 0, 0, 0);
        p = __builtin_amdgcn_mfma_f32_16x16x32_bf16(ea[t][1], bw1, p, 0, 0, 0);
        ushort4 hp4;
        hp4.x = (unsigned short)f2bf(fmaxf(p.x + b1v, 0.f));
        hp4.y = (unsigned short)f2bf(fmaxf(p.y + b1v, 0.f));
        hp4.z = (unsigned short)f2bf(fmaxf(p.z + b1v, 0.f));
        hp4.w = (unsigned short)f2bf(fmaxf(p.w + b1v, 0.f));
        *(ushort4*)(hidT + (hg*16 + m15)*136 + we + t*16 + kq*4) = hp4;
      }
    }
  }

  f32x4 acc[4] = {zero4, zero4, zero4, zero4};
  const int ro0 = (m15*128 + kq*16) ^ ((m15 & 7) << 4);
  const int ro1 = (m15*128 + 64 + kq*16) ^ ((m15 & 7) << 4);

  for (int c = 0; c < 8; ++c) {
    __syncthreads();
    {
      char* wd = (char*)wstage + (w*4)*2048;
      *(f32x4*)(wd + wb0) = s0;          *(f32x4*)(wd + wb1) = s1;
      *(f32x4*)(wd + 2048 + wb0) = s2;   *(f32x4*)(wd + 2048 + wb1) = s3;
      *(f32x4*)(wd + 4096 + wb0) = s4;   *(f32x4*)(wd + 4096 + wb1) = s5;
      *(f32x4*)(wd + 6144 + wb0) = s6;   *(f32x4*)(wd + 6144 + wb1) = s7;
    }
    __syncthreads();
    if (c < 7) {
      const short* pg = w2T + (size_t)((c + 1)*8 + w*4)*4096 + os*1024 + lane*16;
      s0 = *(const f32x4*)(pg);          s1 = *(const f32x4*)(pg + 8);
      s2 = *(const f32x4*)(pg + 4096);   s3 = *(const f32x4*)(pg + 4104);
      s4 = *(const f32x4*)(pg + 8192);   s5 = *(const f32x4*)(pg + 8200);
      s6 = *(const f32x4*)(pg + 12288);  s7 = *(const f32x4*)(pg + 12296);
    }
    #pragma unroll 2
    for (int j = 0; j < 8; ++j) {
      const char* wbp = (const char*)wstage + j*2048;
      bf16x8 W0 = *(const bf16x8*)(wbp + ro0);
      bf16x8 W1 = *(const bf16x8*)(wbp + ro1);
      const unsigned short* hrow =
          (const unsigned short*)hidT + (c*8 + j)*136 + we + kq*4;
      #pragma unroll
      for (int t = 0; t < 4; ++t) {
        f32x4 p = __builtin_amdgcn_mfma_f32_16x16x32_bf16(sfrag[t][0], W0, zero4, 0, 0, 0);
        p = __builtin_amdgcn_mfma_f32_16x16x32_bf16(sfrag[t][1], W1, p, 0, 0, 0);
        ushort4 hu = *(const ushort4*)(hrow + t*16);
        acc[t].x += bf2f(hu.x) * p.x;
        acc[t].y += bf2f(hu.y) * p.y;
        acc[t].z += bf2f(hu.z) * p.z;
        acc[t].w += bf2f(hu.w) * p.w;
      }
    }
  }

  {
    const short* Bp = b2T + (os*16 + m15)*64 + kq*8;
    bf16x8 W0 = *(const bf16x8*)(Bp);
    bf16x8 W1 = *(const bf16x8*)(Bp + 32);
    #pragma unroll
    for (int t = 0; t < 4; ++t) {
      f32x4 p = __builtin_amdgcn_mfma_f32_16x16x32_bf16(sfrag[t][0], W0, zero4, 0, 0, 0);
      p = __builtin_amdgcn_mfma_f32_16x16x32_bf16(sfrag[t][1], W1, p, 0, 0, 0);
      acc[t] += p;
    }
  }

  #pragma unroll
  for (int t = 0; t < 4; ++t) {
    #pragma unroll
    for (int r = 0; r < 4; ++r) {
      int e = we + t*16 + kq*4 + r;
      atomicAdd(&agg[((size_t)os*Nn + dstv[e])*16 + m15], acc[t][r]);
    }
  }
}

// ---------------- fused: m = agg/cnt + out@rootw + rootb ; softmax ; BN stats ----------------
__global__ __launch_bounds__(256) void k_m_fused(
    float* __restrict__ agg, const float* __restrict__ cnt,
    const float* __restrict__ out, const short* __restrict__ rootwT,
    const float* __restrict__ rootb, const float* __restrict__ gnlin,
    float* __restrict__ m, float* __restrict__ sbuf, float* __restrict__ stats) {
  __shared__ float msh[16*65];
  __shared__ float lgsh[16*12];
  __shared__ float ssh[16*16];
  const int tid = threadIdx.x, lane = tid & 63, wave = tid >> 6;
  const int m15 = lane & 15, kq = lane >> 4;
  const int nb = blockIdx.x * 16;
  const f32x4 zero4 = {0.f,0.f,0.f,0.f};
  const int d = wave*16 + m15;   // os = wave, o16 = m15 in agg layout

  bf16x8 b0 = *(const bf16x8*)(rootwT + d*64 + kq*8);
  bf16x8 b1 = *(const bf16x8*)(rootwT + d*64 + 32 + kq*8);
  float rbv = rootb[d];
  {
    const float* sp = out + (size_t)(nb + m15)*64 + kq*8;
    bf16x8 a0 = pack8v(*(const f32x4*)(sp),      *(const f32x4*)(sp + 4));
    bf16x8 a1 = pack8v(*(const f32x4*)(sp + 32), *(const f32x4*)(sp + 36));
    f32x4 p = __builtin_amdgcn_mfma_f32_16x16x32_bf16(a0, b0, zero4, 0, 0, 0);
    p = __builtin_amdgcn_mfma_f32_16x16x32_bf16(a1, b1, p, 0, 0, 0);
    #pragma unroll
    for (int r = 0; r < 4; ++r) {
      int ln = kq*4 + r;
      int node = nb + ln;
      size_t ai = ((size_t)wave*Nn + node)*16 + m15;
      float av = agg[ai];
      agg[ai] = 0.f;
      float mv = av / fmaxf(cnt[node], 1.f) + rbv + p[r];
      m[node*64 + d] = mv;
      msh[ln*65 + d] = mv;
    }
  }
  __syncthreads();

  // logits: 16 nodes x 10 groups
  {
    int n = tid >> 4, g = tid & 15;
    if (g < 10) {
      float lg = 0.f;
      #pragma unroll 8
      for (int k = 0; k < 64; ++k) lg += msh[n*65 + k] * gnlin[k*10 + g];
      lgsh[n*12 + g] = lg;
    }
  }
  __syncthreads();
  // softmax
  {
    int n = tid >> 4, g = tid & 15;
    if (g < 10) {
      float mx = -1e30f;
      #pragma unroll
      for (int gg = 0; gg < 10; ++gg) mx = fmaxf(mx, lgsh[n*12 + gg]);
      float sum = 0.f;
      #pragma unroll
      for (int gg = 0; gg < 10; ++gg) sum += expf(lgsh[n*12 + gg] - mx);
      float sv = expf(lgsh[n*12 + g] - mx) / sum;
      sbuf[(nb + n)*16 + g] = sv;
      ssh[n*16 + g] = sv;
    }
  }
  __syncthreads();
  // BN stat partials over this block's 16 nodes
  for (int c = tid; c < 640; c += 256) {
    int g = c >> 6, dd = c & 63;
    float a1 = 0.f, a2 = 0.f;
    #pragma unroll
    for (int n = 0; n < 16; ++n) {
      float t = ssh[n*16 + g] * msh[n*65 + dd];
      a1 += t; a2 += t*t;
    }
    atomicAdd(&stats[c], a1);
    atomicAdd(&stats[640 + c], a2);
  }
}

// ---------------- fused DGN-finalize + relu + GRU (MFMA) + residual (+pool on last layer) ----------------
__global__ __launch_bounds__(256) void k_gru(
    const float* __restrict__ m, const float* __restrict__ sbuf,
    const float* __restrict__ stats, const float* __restrict__ gamma,
    const float* __restrict__ beta, const short* __restrict__ gwihB,
    const short* __restrict__ gwhhB, const float* __restrict__ bih,
    const float* __restrict__ bhh, float* __restrict__ h,
    float* __restrict__ out,
    const int* __restrict__ batch, float* __restrict__ pooled,
    float* __restrict__ pcnt, int doPool) {
  __shared__ __align__(16) float mrsh[16*68];
  __shared__ float igsh[640];
  __shared__ float Bsh[64];
  __shared__ float ssh[256];
  const int tid = threadIdx.x, lane = tid & 63, wave = tid >> 6;
  const int m15 = lane & 15, kq = lane >> 4;
  const int nb = blockIdx.x * 16;
  const f32x4 zero4 = {0.f,0.f,0.f,0.f};
  const float invN = 1.f / (float)Nn;

  if (tid < 64) {
    float bacc = 0.f;
    #pragma unroll
    for (int g = 0; g < 10; ++g) {
      int c = g*64 + tid;
      float mu = stats[c] * invN;
      float var = stats[640 + c] * invN - mu*mu;
      float ig = (1.0f / sqrtf(var + EPSf)) * gamma[c];
      igsh[c] = ig;
      bacc += beta[c] - mu * ig;
    }
    Bsh[tid] = bacc;
  }
  ssh[tid] = sbuf[nb*16 + tid];
  __syncthreads();

  for (int idx = tid; idx < 1024; idx += 256) {
    int n = idx >> 6, dd = idx & 63;
    float mv = m[(nb + n)*64 + dd];
    float SA = 0.f;
    #pragma unroll
    for (int g = 0; g < 10; ++g) SA += ssh[n*16 + g] * igsh[g*64 + dd];
    mrsh[n*68 + dd] = fmaxf(mv * (1.f + LAMf*SA) + LAMf*Bsh[dd], 0.f);
  }
  __syncthreads();

  // fragments (single 16-node tile)
  bf16x8 mrf[2], hf[2];
  {
    const float* mp = mrsh + m15*68 + kq*8;
    const float* hp = h + (size_t)(nb + m15)*64 + kq*8;
    #pragma unroll
    for (int ks = 0; ks < 2; ++ks) {
      mrf[ks] = pack8v(*(const f32x4*)(mp + ks*32), *(const f32x4*)(mp + ks*32 + 4));
      hf[ks]  = pack8v(*(const f32x4*)(hp + ks*32), *(const f32x4*)(hp + ks*32 + 4));
    }
  }
  const int d = wave*16 + m15;
  f32x4 gi[3], gh[3];
  #pragma unroll
  for (int p = 0; p < 3; ++p) {
    int j = p*64 + d;
    bf16x8 bi0 = *(const bf16x8*)(gwihB + j*64 + kq*8);
    bf16x8 bi1 = *(const bf16x8*)(gwihB + j*64 + 32 + kq*8);
    bf16x8 bh0 = *(const bf16x8*)(gwhhB + j*64 + kq*8);
    bf16x8 bh1 = *(const bf16x8*)(gwhhB + j*64 + 32 + kq*8);
    f32x4 a = __builtin_amdgcn_mfma_f32_16x16x32_bf16(mrf[0], bi0, zero4, 0, 0, 0);
    gi[p] = __builtin_amdgcn_mfma_f32_16x16x32_bf16(mrf[1], bi1, a, 0, 0, 0);
    f32x4 b = __builtin_amdgcn_mfma_f32_16x16x32_bf16(hf[0], bh0, zero4, 0, 0, 0);
    gh[p] = __builtin_amdgcn_mfma_f32_16x16x32_bf16(hf[1], bh1, b, 0, 0, 0);
  }
  float bir = bih[d],      bhr = bhh[d];
  float biz = bih[64 + d], bhz = bhh[64 + d];
  float bin = bih[128 + d], bhn = bhh[128 + d];
  __syncthreads();   // all h-fragment reads done before any h write
  #pragma unroll
  for (int r = 0; r < 4; ++r) {
    int node = nb + kq*4 + r;
    float rr = sigm(gi[0][r] + bir + gh[0][r] + bhr);
    float z  = sigm(gi[1][r] + biz + gh[1][r] + bhz);
    float nn = tanhf(gi[2][r] + bin + rr * (gh[2][r] + bhn));
    float hv = h[node*64 + d];
    float hn = (1.f - z) * nn + z * hv;
    h[node*64 + d] = hn;
    float ov = hn + out[node*64 + d];
    out[node*64 + d] = ov;
    if (doPool) {
      int b = batch[node];
      atomicAdd(&pooled[b*64 + d], ov);
      if (d == 0) atomicAdd(&pcnt[b], 1.f);
    }
  }
}

// ---------------- post FC + output ----------------
__global__ void k_final(const float* __restrict__ pooled, const float* __restrict__ pcnt,
                        const float* __restrict__ postW, const float* __restrict__ postb,
                        const float* __restrict__ outW, const float* __restrict__ outb,
                        float* __restrict__ y) {
  int b = blockIdx.x, d = threadIdx.x;
  __shared__ float pl[64];
  float c = fmaxf(pcnt[b], 1.f);
  pl[d] = pooled[b*64 + d] / c;
  __syncthreads();
  float acc = postb[d];
  #pragma unroll 8
  for (int k = 0; k < 64; ++k) acc += pl[k] * postW[k*64 + d];
  acc = fmaxf(acc, 0.f);
  float v = acc * outW[d];
  #pragma unroll
  for (int off = 32; off > 0; off >>= 1) v += __shfl_down(v, off, 64);
  if (d == 0) y[b] = v + outb[0];
}

extern "C" void kernel_launch(void* const* d_in, const int* in_sizes, int n_in,
                              void* d_out, int out_size, void* d_ws, size_t ws_size,
                              hipStream_t stream) {
  (void)in_sizes; (void)n_in; (void)out_size; (void)ws_size;
  const float* x        = (const float*)d_in[0];
  const float* edge_attr= (const float*)d_in[1];
  const float* preW     = (const float*)d_in[2];
  const float* preb     = (const float*)d_in[3];
  const float* ew1      = (const float*)d_in[4];
  const float* eb1      = (const float*)d_in[5];
  const float* ew2      = (const float*)d_in[6];
  const float* eb2      = (const float*)d_in[7];
  const float* rootw    = (const float*)d_in[8];
  const float* rootb    = (const float*)d_in[9];
  const float* gwih     = (const float*)d_in[10];
  const float* gwhh     = (const float*)d_in[11];
  const float* gbih     = (const float*)d_in[12];
  const float* gbhh     = (const float*)d_in[13];
  const float* gnlin    = (const float*)d_in[14];
  const float* gngamma  = (const float*)d_in[15];
  const float* gnbeta   = (const float*)d_in[16];
  const float* postW    = (const float*)d_in[17];
  const float* postb    = (const float*)d_in[18];
  const float* outW     = (const float*)d_in[19];
  const float* outb     = (const float*)d_in[20];
  const int*   eidx     = (const int*)d_in[21];
  const int*   batch    = (const int*)d_in[22];
  const int* src = eidx;
  const int* dst = eidx + Ee;
  float* y = (float*)d_out;

  float* ws     = (float*)d_ws;
  float* out    = ws;                     // N*64
  float* hbuf   = out    + Nn*64;
  float* mbuf   = hbuf   + Nn*64;
  float* sbuf   = mbuf   + Nn*64;         // N*16
  float* agg    = sbuf   + Nn*16;         // N*64 ([os][node][16] layout)
  float* stats  = agg    + Nn*64;         // 2048
  float* cnt    = stats  + 2048;          // N
  float* pooled = cnt    + Nn;            // N (>= B*64)
  float* pcnt   = pooled + Nn;            // 64
  float* bfbase = pcnt   + 64;
  short* w1T    = (short*)bfbase;         // 3*4096
  short* b2T    = w1T    + 3*4096;
  short* w2T    = b2T    + 3*4096;        // 3*262144
  short* rootwT = w2T    + 3*262144;      // 3*4096
  short* gwihB  = rootwT + 3*4096;        // 3*12288
  short* gwhhB  = gwihB  + 3*12288;       // 3*12288
  short* preWT  = gwhhB  + 3*12288;       // 8192

  // single memset: agg + stats + cnt + pooled + pcnt (contiguous)
  hipMemsetAsync(agg, 0, (Nn*64 + 2048 + Nn + Nn + 64)*sizeof(float), stream);

  k_prep<<<337, 256, 0, stream>>>(ew1, ew2, eb2, rootw, gwih, gwhh, preW, preb,
                                  postW, postb, outW, outb, dst,
                                  w1T, b2T, w2T, rootwT, gwihB, gwhhB, preWT,
                                  cnt, y);
  k_pre<<<Nn/16, 256, 0, stream>>>(x, preWT, preb, out, hbuf);

  for (int i = 0; i < 3; ++i) {
    k_msg<<<(Ee/128)*4, 128, 0, stream>>>(out, edge_attr,
                                     w1T + i*4096, eb1 + i*64,
                                     w2T + i*262144, b2T + i*4096,
                                     src, dst, agg, stats);
    k_m_fused<<<Nn/16, 256, 0, stream>>>(agg, cnt, out, rootwT + i*4096,
                                         rootb + i*64, gnlin + i*640, mbuf, sbuf, stats);
    k_gru<<<Nn/16, 256, 0, stream>>>(mbuf, sbuf, stats, gngamma + i*640, gnbeta + i*640,
                                     gwihB + i*12288, gwhhB + i*12288,
                                     gbih + i*192, gbhh + i*192, hbuf, out,
                                     batch, pooled, pcnt, (i == 2) ? 1 : 0);
  }

  k_final<<<Bb, 64, 0, stream>>>(pooled, pcnt, postW, postb, outW, outb, y);
}

// Round 13
// 304.298 us; speedup vs baseline: 1.2584x; 1.0109x over previous
//
#include <hip/hip_runtime.h>
#include <math.h>

#define Nn 4096
#define Ee 32768
#define Bb 64
#define FINc 128
#define Dd 64
#define SIGf 0.15f
#define LAMf 0.01f
#define EPSf 1e-5f

typedef __attribute__((ext_vector_type(8))) short bf16x8;
typedef __attribute__((ext_vector_type(4))) float f32x4;

__device__ inline short f2bf(float f) {
  union { float f; unsigned u; } v; v.f = f;
  unsigned r = v.u + 0x7fffu + ((v.u >> 16) & 1u);
  return (short)(r >> 16);
}
__device__ inline float bf2f(unsigned short s) {
  union { unsigned u; float f; } v; v.u = ((unsigned)s) << 16; return v.f;
}
__device__ inline bf16x8 pack8v(f32x4 a, f32x4 b) {
  bf16x8 r;
  r[0]=f2bf(a.x); r[1]=f2bf(a.y); r[2]=f2bf(a.z); r[3]=f2bf(a.w);
  r[4]=f2bf(b.x); r[5]=f2bf(b.y); r[6]=f2bf(b.z); r[7]=f2bf(b.w);
  return r;
}
__device__ inline float sigm(float x) { return 1.f / (1.f + expf(-x)); }

// ---------------- prep: w2 transpose + packs + in-degree + tkl + pre-FC ----------------
// blocks 0..191   : w2 page transpose (LDS tile, coalesced both sides)
// blocks 192..335 : small weight packs + edge in-degree count
// block 336       : tkl scalar (y[64])
// blocks 337..592 : pre-FC out = relu(x @ preW + preb), 16 nodes each
//                   (B-fragment read directly from preW f32 — no preWT dep,
//                    so these blocks are order-independent; saves the k_pre launch)
__global__ __launch_bounds__(256) void k_prep(
    const float* __restrict__ w1, const float* __restrict__ w2,
    const float* __restrict__ b2, const float* __restrict__ rootw,
    const float* __restrict__ gwih, const float* __restrict__ gwhh,
    const float* __restrict__ preW, const float* __restrict__ preb,
    const float* __restrict__ postW, const float* __restrict__ postb,
    const float* __restrict__ outW, const float* __restrict__ outb,
    const int* __restrict__ dstIdx, const float* __restrict__ x,
    short* __restrict__ w1T, short* __restrict__ b2T,
    short* __restrict__ w2T, short* __restrict__ rootwT,
    short* __restrict__ gwihB, short* __restrict__ gwhhB,
    float* __restrict__ cnt, float* __restrict__ out,
    float* __restrict__ hbuf, float* __restrict__ y) {
  const int tid = threadIdx.x;
  const int bid = blockIdx.x;
  __shared__ float tile[64][65];
  __shared__ float red[256];

  if (bid < 192) {
    // transpose one 64x64 page: w2T[l][h][o][f] = w2[l][h][f][o]
    const float* srcp = w2 + (size_t)bid*4096;
    #pragma unroll
    for (int r = 0; r < 16; ++r) {
      int i2 = r*256 + tid;
      tile[i2 >> 6][i2 & 63] = srcp[i2];
    }
    __syncthreads();
    short* dstp = w2T + (size_t)bid*4096;
    #pragma unroll
    for (int r = 0; r < 16; ++r) {
      int i2 = r*256 + tid;
      dstp[i2] = f2bf(tile[i2 & 63][i2 >> 6]);
    }
  } else if (bid < 336) {
    int idx = (bid - 192)*256 + tid;
    if (idx < 3*64*64) {
      int f = idx & 63, h = (idx >> 6) & 63, l = idx >> 12;
      w1T[idx] = f2bf(w1[l*4096 + f*64 + h]);          // w1T[l][h][f]
      b2T[idx] = f2bf(b2[l*4096 + f*64 + h]);          // b2T[l][o][f]
      rootwT[idx] = f2bf(rootw[l*4096 + f*64 + h]);    // rootwT[l][d][k]
    }
    if (idx < 3*192*64) {
      gwihB[idx] = f2bf(gwih[idx]);
      gwhhB[idx] = f2bf(gwhh[idx]);
    }
    if (idx < Ee) atomicAdd(&cnt[dstIdx[idx]], 1.0f);
  } else if (bid == 336) {
    const float logc = logf(SIGf * sqrtf(6.28318530717958647692f));
    const float c2 = 0.5f / (SIGf * SIGf);
    float acc = 0.f;
    for (int i = tid; i < FINc*Dd; i += 256) { float w = preW[i];  acc += c2*w*w + logc; }
    for (int i = tid; i < Dd; i += 256)      { float w = preb[i];  acc += c2*w*w + logc; }
    for (int i = tid; i < Dd*Dd; i += 256)   { float w = postW[i]; acc += c2*w*w + logc; }
    for (int i = tid; i < Dd; i += 256)      { float w = postb[i]; acc += c2*w*w + logc; }
    for (int i = tid; i < Dd; i += 256)      { float w = outW[i];  acc += c2*w*w + logc; }
    if (tid == 0)                            { float w = outb[0];  acc += c2*w*w + logc; }
    red[tid] = acc; __syncthreads();
    for (int s = 128; s > 0; s >>= 1) { if (tid < s) red[tid] += red[tid+s]; __syncthreads(); }
    if (tid == 0) y[Bb] = red[0];
  } else {
    // pre-FC: 16 nodes per block
    const int lane = tid & 63, wave = tid >> 6;
    const int m15 = lane & 15, kq = lane >> 4;
    const int nb = (bid - 337) * 16;
    const f32x4 zero4 = {0.f,0.f,0.f,0.f};
    const int d = wave*16 + m15;
    const float* xp = x + (size_t)(nb + m15)*128 + kq*8;
    f32x4 p = zero4;
    #pragma unroll
    for (int c = 0; c < 4; ++c) {
      bf16x8 bw;
      #pragma unroll
      for (int j = 0; j < 8; ++j)
        bw[j] = f2bf(preW[(c*32 + kq*8 + j)*64 + d]);   // preW^T fragment, direct
      bf16x8 a = pack8v(*(const f32x4*)(xp + c*32), *(const f32x4*)(xp + c*32 + 4));
      p = __builtin_amdgcn_mfma_f32_16x16x32_bf16(a, bw, p, 0, 0, 0);
    }
    float bv = preb[d];
    #pragma unroll
    for (int r = 0; r < 4; ++r) {
      int node = nb + kq*4 + r;
      float v = fmaxf(p[r] + bv, 0.f);
      out[node*64 + d] = v;
      hbuf[node*64 + d] = v;
    }
  }
}

// ---------------- fused edge-MLP + bilinear message GEMM (MFMA) + scatter ----------------
// 128 edges x 16 o-values per block, 2 waves; grid = 256 ebi x 4 os = 1024
// -> 4 independent blocks/CU, small barrier domains, reg-staged w2 through
// LDS with XOR swizzle (vmcnt wait lands at next ds_write, a full compute
// phase after issue -> latency hidden). Clean per-(node,o)-once 64B atomic
// segments. [Round-8 verified structure.]
__global__ __launch_bounds__(128) void k_msg(
    const float* __restrict__ out, const float* __restrict__ edge_attr,
    const short* __restrict__ w1T, const float* __restrict__ b1,
    const short* __restrict__ w2T, const short* __restrict__ b2T,
    const int* __restrict__ src, const int* __restrict__ dst,
    float* __restrict__ agg, float* __restrict__ stats) {
  __shared__ short hidT[64*136];
  __shared__ __align__(16) short wstage[8192];
  __shared__ int srcv[128];
  __shared__ int dstv[128];

  const int tid  = threadIdx.x;
  const int lane = tid & 63;
  const int w    = tid >> 6;
  const int m15  = lane & 15;
  const int kq   = lane >> 4;
  const int ebi  = blockIdx.x & 255;
  const int os   = blockIdx.x >> 8;
  const int ebase = ebi * 128;
  const int we   = w*64;

  srcv[tid] = src[ebase + tid];
  dstv[tid] = dst[ebase + tid];
  if (blockIdx.x == 0) {
    for (int i = tid; i < 1280; i += 128) stats[i] = 0.f;
  }
  __syncthreads();

  const f32x4 zero4 = {0.f, 0.f, 0.f, 0.f};

  f32x4 s0, s1, s2, s3, s4, s5, s6, s7;
  {
    const short* pg = w2T + (size_t)(w*4)*4096 + os*1024 + lane*16;
    s0 = *(const f32x4*)(pg);          s1 = *(const f32x4*)(pg + 8);
    s2 = *(const f32x4*)(pg + 4096);   s3 = *(const f32x4*)(pg + 4104);
    s4 = *(const f32x4*)(pg + 8192);   s5 = *(const f32x4*)(pg + 8200);
    s6 = *(const f32x4*)(pg + 12288);  s7 = *(const f32x4*)(pg + 12296);
  }
  const int wb0 = (lane*32) ^ ((((lane*32) >> 7) & 7) << 4);
  const int wb1 = (lane*32 + 16) ^ ((((lane*32) >> 7) & 7) << 4);

  bf16x8 sfrag[4][2];
  #pragma unroll
  for (int t = 0; t < 4; ++t) {
    int node = srcv[we + t*16 + m15];
    const float* sp = out + node*64 + kq*8;
    #pragma unroll
    for (int ks = 0; ks < 2; ++ks)
      sfrag[t][ks] = pack8v(*(const f32x4*)(sp + ks*32), *(const f32x4*)(sp + ks*32 + 4));
  }

  {
    bf16x8 ea[4][2];
    #pragma unroll
    for (int t = 0; t < 4; ++t) {
      const float* ep = edge_attr + (size_t)(ebase + we + t*16 + m15)*64 + kq*8;
      ea[t][0] = pack8v(*(const f32x4*)(ep),      *(const f32x4*)(ep + 4));
      ea[t][1] = pack8v(*(const f32x4*)(ep + 32), *(const f32x4*)(ep + 36));
    }
    #pragma unroll
    for (int hg = 0; hg < 4; ++hg) {
      const short* wp = w1T + (hg*16 + m15)*64 + kq*8;
      bf16x8 bw0 = *(const bf16x8*)(wp);
      bf16x8 bw1 = *(const bf16x8*)(wp + 32);
      float b1v = b1[hg*16 + m15];
      #pragma unroll
      for (int t = 0; t < 4; ++t) {
        f32x4 p = __builtin_amdgcn_mfma_f32_16x16x32_bf16(ea[t][0], bw0, zero4, 0, 0, 0);
        p = __builtin_amdgcn_mfma_f32_16x16x32_bf16(ea[t][1], bw1, p, 0, 0, 0);
        ushort4 hp4;
        hp4.x = (unsigned short)f2bf(fmaxf(p.x + b1v, 0.f));
        hp4.y = (unsigned short)f2bf(fmaxf(p.y + b1v, 0.f));
        hp4.z = (unsigned short)f2bf(fmaxf(p.z + b1v, 0.f));
        hp4.w = (unsigned short)f2bf(fmaxf(p.w + b1v, 0.f));
        *(ushort4*)(hidT + (hg*16 + m15)*136 + we + t*16 + kq*4) = hp4;
      }
    }
  }

  f32x4 acc[4] = {zero4, zero4, zero4, zero4};
  const int ro0 = (m15*128 + kq*16) ^ ((m15 & 7) << 4);
  const int ro1 = (m15*128 + 64 + kq*16) ^ ((m15 & 7) << 4);

  for (int c = 0; c < 8; ++c) {
    __syncthreads();
    {
      char* wd = (char*)wstage + (w*4)*2048;
      *(f32x4*)(wd + wb0) = s0;          *(f32x4*)(wd + wb1) = s1;
      *(f32x4*)(wd + 2048 + wb0) = s2;   *(f32x4*)(wd + 2048 + wb1) = s3;
      *(f32x4*)(wd + 4096 + wb0) = s4;   *(f32x4*)(wd + 4096 + wb1) = s5;
      *(f32x4*)(wd + 6144 + wb0) = s6;   *(f32x4*)(wd + 6144 + wb1) = s7;
    }
    __syncthreads();
    if (c < 7) {
      const short* pg = w2T + (size_t)((c + 1)*8 + w*4)*4096 + os*1024 + lane*16;
      s0 = *(const f32x4*)(pg);          s1 = *(const f32x4*)(pg + 8);
      s2 = *(const f32x4*)(pg + 4096);   s3 = *(const f32x4*)(pg + 4104);
      s4 = *(const f32x4*)(pg + 8192);   s5 = *(const f32x4*)(pg + 8200);
      s6 = *(const f32x4*)(pg + 12288);  s7 = *(const f32x4*)(pg + 12296);
    }
    #pragma unroll 2
    for (int j = 0; j < 8; ++j) {
      const char* wbp = (const char*)wstage + j*2048;
      bf16x8 W0 = *(const bf16x8*)(wbp + ro0);
      bf16x8 W1 = *(const bf16x8*)(wbp + ro1);
      const unsigned short* hrow =
          (const unsigned short*)hidT + (c*8 + j)*136 + we + kq*4;
      #pragma unroll
      for (int t = 0; t < 4; ++t) {
        f32x4 p = __builtin_amdgcn_mfma_f32_16x16x32_bf16(sfrag[t][0], W0, zero4, 0, 0, 0);
        p = __builtin_amdgcn_mfma_f32_16x16x32_bf16(sfrag[t][1], W1, p, 0, 0, 0);
        ushort4 hu = *(const ushort4*)(hrow + t*16);
        f32x4 hvf;
        hvf.x = bf2f(hu.x); hvf.y = bf2f(hu.y);
        hvf.z = bf2f(hu.z); hvf.w = bf2f(hu.w);
        acc[t] += hvf * p;               // packed-FMA friendly form
      }
    }
  }

  {
    const short* Bp = b2T + (os*16 + m15)*64 + kq*8;
    bf16x8 W0 = *(const bf16x8*)(Bp);
    bf16x8 W1 = *(const bf16x8*)(Bp + 32);
    #pragma unroll
    for (int t = 0; t < 4; ++t) {
      f32x4 p = __builtin_amdgcn_mfma_f32_16x16x32_bf16(sfrag[t][0], W0, zero4, 0, 0, 0);
      p = __builtin_amdgcn_mfma_f32_16x16x32_bf16(sfrag[t][1], W1, p, 0, 0, 0);
      acc[t] += p;
    }
  }

  #pragma unroll
  for (int t = 0; t < 4; ++t) {
    #pragma unroll
    for (int r = 0; r < 4; ++r) {
      int e = we + t*16 + kq*4 + r;
      atomicAdd(&agg[((size_t)os*Nn + dstv[e])*16 + m15], acc[t][r]);
    }
  }
}

// ---------------- fused: m = agg/cnt + out@rootw + rootb ; softmax ; BN stats ----------------
__global__ __launch_bounds__(256) void k_m_fused(
    float* __restrict__ agg, const float* __restrict__ cnt,
    const float* __restrict__ out, const short* __restrict__ rootwT,
    const float* __restrict__ rootb, const float* __restrict__ gnlin,
    float* __restrict__ m, float* __restrict__ sbuf, float* __restrict__ stats) {
  __shared__ float msh[16*65];
  __shared__ float lgsh[16*12];
  __shared__ float ssh[16*16];
  const int tid = threadIdx.x, lane = tid & 63, wave = tid >> 6;
  const int m15 = lane & 15, kq = lane >> 4;
  const int nb = blockIdx.x * 16;
  const f32x4 zero4 = {0.f,0.f,0.f,0.f};
  const int d = wave*16 + m15;   // os = wave, o16 = m15 in agg layout

  bf16x8 b0 = *(const bf16x8*)(rootwT + d*64 + kq*8);
  bf16x8 b1 = *(const bf16x8*)(rootwT + d*64 + 32 + kq*8);
  float rbv = rootb[d];
  {
    const float* sp = out + (size_t)(nb + m15)*64 + kq*8;
    bf16x8 a0 = pack8v(*(const f32x4*)(sp),      *(const f32x4*)(sp + 4));
    bf16x8 a1 = pack8v(*(const f32x4*)(sp + 32), *(const f32x4*)(sp + 36));
    f32x4 p = __builtin_amdgcn_mfma_f32_16x16x32_bf16(a0, b0, zero4, 0, 0, 0);
    p = __builtin_amdgcn_mfma_f32_16x16x32_bf16(a1, b1, p, 0, 0, 0);
    #pragma unroll
    for (int r = 0; r < 4; ++r) {
      int ln = kq*4 + r;
      int node = nb + ln;
      size_t ai = ((size_t)wave*Nn + node)*16 + m15;
      float av = agg[ai];
      agg[ai] = 0.f;
      float mv = av / fmaxf(cnt[node], 1.f) + rbv + p[r];
      m[node*64 + d] = mv;
      msh[ln*65 + d] = mv;
    }
  }
  __syncthreads();

  // logits: 16 nodes x 10 groups
  {
    int n = tid >> 4, g = tid & 15;
    if (g < 10) {
      float lg = 0.f;
      #pragma unroll 8
      for (int k = 0; k < 64; ++k) lg += msh[n*65 + k] * gnlin[k*10 + g];
      lgsh[n*12 + g] = lg;
    }
  }
  __syncthreads();
  // softmax
  {
    int n = tid >> 4, g = tid & 15;
    if (g < 10) {
      float mx = -1e30f;
      #pragma unroll
      for (int gg = 0; gg < 10; ++gg) mx = fmaxf(mx, lgsh[n*12 + gg]);
      float sum = 0.f;
      #pragma unroll
      for (int gg = 0; gg < 10; ++gg) sum += expf(lgsh[n*12 + gg] - mx);
      float sv = expf(lgsh[n*12 + g] - mx) / sum;
      sbuf[(nb + n)*16 + g] = sv;
      ssh[n*16 + g] = sv;
    }
  }
  __syncthreads();
  // BN stat partials over this block's 16 nodes
  for (int c = tid; c < 640; c += 256) {
    int g = c >> 6, dd = c & 63;
    float a1 = 0.f, a2 = 0.f;
    #pragma unroll
    for (int n = 0; n < 16; ++n) {
      float t = ssh[n*16 + g] * msh[n*65 + dd];
      a1 += t; a2 += t*t;
    }
    atomicAdd(&stats[c], a1);
    atomicAdd(&stats[640 + c], a2);
  }
}

// ---------------- fused DGN-finalize + relu + GRU (MFMA) + residual (+pool on last layer) ----------------
__global__ __launch_bounds__(256) void k_gru(
    const float* __restrict__ m, const float* __restrict__ sbuf,
    const float* __restrict__ stats, const float* __restrict__ gamma,
    const float* __restrict__ beta, const short* __restrict__ gwihB,
    const short* __restrict__ gwhhB, const float* __restrict__ bih,
    const float* __restrict__ bhh, float* __restrict__ h,
    float* __restrict__ out,
    const int* __restrict__ batch, float* __restrict__ pooled,
    float* __restrict__ pcnt, int doPool) {
  __shared__ __align__(16) float mrsh[16*68];
  __shared__ float igsh[640];
  __shared__ float Bsh[64];
  __shared__ float ssh[256];
  const int tid = threadIdx.x, lane = tid & 63, wave = tid >> 6;
  const int m15 = lane & 15, kq = lane >> 4;
  const int nb = blockIdx.x * 16;
  const f32x4 zero4 = {0.f,0.f,0.f,0.f};
  const float invN = 1.f / (float)Nn;

  if (tid < 64) {
    float bacc = 0.f;
    #pragma unroll
    for (int g = 0; g < 10; ++g) {
      int c = g*64 + tid;
      float mu = stats[c] * invN;
      float var = stats[640 + c] * invN - mu*mu;
      float ig = (1.0f / sqrtf(var + EPSf)) * gamma[c];
      igsh[c] = ig;
      bacc += beta[c] - mu * ig;
    }
    Bsh[tid] = bacc;
  }
  ssh[tid] = sbuf[nb*16 + tid];
  __syncthreads();

  for (int idx = tid; idx < 1024; idx += 256) {
    int n = idx >> 6, dd = idx & 63;
    float mv = m[(nb + n)*64 + dd];
    float SA = 0.f;
    #pragma unroll
    for (int g = 0; g < 10; ++g) SA += ssh[n*16 + g] * igsh[g*64 + dd];
    mrsh[n*68 + dd] = fmaxf(mv * (1.f + LAMf*SA) + LAMf*Bsh[dd], 0.f);
  }
  __syncthreads();

  // fragments (single 16-node tile)
  bf16x8 mrf[2], hf[2];
  {
    const float* mp = mrsh + m15*68 + kq*8;
    const float* hp = h + (size_t)(nb + m15)*64 + kq*8;
    #pragma unroll
    for (int ks = 0; ks < 2; ++ks) {
      mrf[ks] = pack8v(*(const f32x4*)(mp + ks*32), *(const f32x4*)(mp + ks*32 + 4));
      hf[ks]  = pack8v(*(const f32x4*)(hp + ks*32), *(const f32x4*)(hp + ks*32 + 4));
    }
  }
  const int d = wave*16 + m15;
  f32x4 gi[3], gh[3];
  #pragma unroll
  for (int p = 0; p < 3; ++p) {
    int j = p*64 + d;
    bf16x8 bi0 = *(const bf16x8*)(gwihB + j*64 + kq*8);
    bf16x8 bi1 = *(const bf16x8*)(gwihB + j*64 + 32 + kq*8);
    bf16x8 bh0 = *(const bf16x8*)(gwhhB + j*64 + kq*8);
    bf16x8 bh1 = *(const bf16x8*)(gwhhB + j*64 + 32 + kq*8);
    f32x4 a = __builtin_amdgcn_mfma_f32_16x16x32_bf16(mrf[0], bi0, zero4, 0, 0, 0);
    gi[p] = __builtin_amdgcn_mfma_f32_16x16x32_bf16(mrf[1], bi1, a, 0, 0, 0);
    f32x4 b = __builtin_amdgcn_mfma_f32_16x16x32_bf16(hf[0], bh0, zero4, 0, 0, 0);
    gh[p] = __builtin_amdgcn_mfma_f32_16x16x32_bf16(hf[1], bh1, b, 0, 0, 0);
  }
  float bir = bih[d],      bhr = bhh[d];
  float biz = bih[64 + d], bhz = bhh[64 + d];
  float bin = bih[128 + d], bhn = bhh[128 + d];
  __syncthreads();   // all h-fragment reads done before any h write
  #pragma unroll
  for (int r = 0; r < 4; ++r) {
    int node = nb + kq*4 + r;
    float rr = sigm(gi[0][r] + bir + gh[0][r] + bhr);
    float z  = sigm(gi[1][r] + biz + gh[1][r] + bhz);
    float nn = tanhf(gi[2][r] + bin + rr * (gh[2][r] + bhn));
    float hv = h[node*64 + d];
    float hn = (1.f - z) * nn + z * hv;
    h[node*64 + d] = hn;
    float ov = hn + out[node*64 + d];
    out[node*64 + d] = ov;
    if (doPool) {
      int b = batch[node];
      atomicAdd(&pooled[b*64 + d], ov);
      if (d == 0) atomicAdd(&pcnt[b], 1.f);
    }
  }
}

// ---------------- post FC + output ----------------
__global__ void k_final(const float* __restrict__ pooled, const float* __restrict__ pcnt,
                        const float* __restrict__ postW, const float* __restrict__ postb,
                        const float* __restrict__ outW, const float* __restrict__ outb,
                        float* __restrict__ y) {
  int b = blockIdx.x, d = threadIdx.x;
  __shared__ float pl[64];
  float c = fmaxf(pcnt[b], 1.f);
  pl[d] = pooled[b*64 + d] / c;
  __syncthreads();
  float acc = postb[d];
  #pragma unroll 8
  for (int k = 0; k < 64; ++k) acc += pl[k] * postW[k*64 + d];
  acc = fmaxf(acc, 0.f);
  float v = acc * outW[d];
  #pragma unroll
  for (int off = 32; off > 0; off >>= 1) v += __shfl_down(v, off, 64);
  if (d == 0) y[b] = v + outb[0];
}

extern "C" void kernel_launch(void* const* d_in, const int* in_sizes, int n_in,
                              void* d_out, int out_size, void* d_ws, size_t ws_size,
                              hipStream_t stream) {
  (void)in_sizes; (void)n_in; (void)out_size; (void)ws_size;
  const float* x        = (const float*)d_in[0];
  const float* edge_attr= (const float*)d_in[1];
  const float* preW     = (const float*)d_in[2];
  const float* preb     = (const float*)d_in[3];
  const float* ew1      = (const float*)d_in[4];
  const float* eb1      = (const float*)d_in[5];
  const float* ew2      = (const float*)d_in[6];
  const float* eb2      = (const float*)d_in[7];
  const float* rootw    = (const float*)d_in[8];
  const float* rootb    = (const float*)d_in[9];
  const float* gwih     = (const float*)d_in[10];
  const float* gwhh     = (const float*)d_in[11];
  const float* gbih     = (const float*)d_in[12];
  const float* gbhh     = (const float*)d_in[13];
  const float* gnlin    = (const float*)d_in[14];
  const float* gngamma  = (const float*)d_in[15];
  const float* gnbeta   = (const float*)d_in[16];
  const float* postW    = (const float*)d_in[17];
  const float* postb    = (const float*)d_in[18];
  const float* outW     = (const float*)d_in[19];
  const float* outb     = (const float*)d_in[20];
  const int*   eidx     = (const int*)d_in[21];
  const int*   batch    = (const int*)d_in[22];
  const int* src = eidx;
  const int* dst = eidx + Ee;
  float* y = (float*)d_out;

  float* ws     = (float*)d_ws;
  float* out    = ws;                     // N*64
  float* hbuf   = out    + Nn*64;
  float* mbuf   = hbuf   + Nn*64;
  float* sbuf   = mbuf   + Nn*64;         // N*16
  float* agg    = sbuf   + Nn*16;         // N*64 ([os][node][16] layout)
  float* stats  = agg    + Nn*64;         // 2048
  float* cnt    = stats  + 2048;          // N
  float* pooled = cnt    + Nn;            // N (>= B*64)
  float* pcnt   = pooled + Nn;            // 64
  float* bfbase = pcnt   + 64;
  short* w1T    = (short*)bfbase;         // 3*4096
  short* b2T    = w1T    + 3*4096;
  short* w2T    = b2T    + 3*4096;        // 3*262144
  short* rootwT = w2T    + 3*262144;      // 3*4096
  short* gwihB  = rootwT + 3*4096;        // 3*12288
  short* gwhhB  = gwihB  + 3*12288;       // 3*12288

  // single memset: agg + stats + cnt + pooled + pcnt (contiguous)
  hipMemsetAsync(agg, 0, (Nn*64 + 2048 + Nn + Nn + 64)*sizeof(float), stream);

  k_prep<<<593, 256, 0, stream>>>(ew1, ew2, eb2, rootw, gwih, gwhh, preW, preb,
                                  postW, postb, outW, outb, dst, x,
                                  w1T, b2T, w2T, rootwT, gwihB, gwhhB,
                                  cnt, out, hbuf, y);

  for (int i = 0; i < 3; ++i) {
    k_msg<<<(Ee/128)*4, 128, 0, stream>>>(out, edge_attr,
                                     w1T + i*4096, eb1 + i*64,
                                     w2T + i*262144, b2T + i*4096,
                                     src, dst, agg, stats);
    k_m_fused<<<Nn/16, 256, 0, stream>>>(agg, cnt, out, rootwT + i*4096,
                                         rootb + i*64, gnlin + i*640, mbuf, sbuf, stats);
    k_gru<<<Nn/16, 256, 0, stream>>>(mbuf, sbuf, stats, gngamma + i*640, gnbeta + i*640,
                                     gwihB + i*12288, gwhhB + i*12288,
                                     gbih + i*192, gbhh + i*192, hbuf, out,
                                     batch, pooled, pcnt, (i == 2) ? 1 : 0);
  }

  k_final<<<Bb, 64, 0, stream>>>(pooled, pcnt, postW, postb, outW, outb, y);
}